// Round 4
// baseline (234.293 us; speedup 1.0000x reference)
//
#include <hip/hip_runtime.h>

#define TPB 256

typedef float v2f __attribute__((ext_vector_type(2)));

// ---- d_ws float layout ----
// pre [2][170][52] : W1[:, :50] @ emb[c] + b1   (52-padded, pads 0)
// w1g [2][52]      : W1[j][50] glicko column    (pads 0)
// w2t [2][50][28]  : W2^T rows [j][m<=28]       (pads 0; 112 B rows, 16B-aligned)
// w3t [2][25][12]  : W3^T rows [m][t<=12]       (pads 0; 48 B rows)
// b2p [2][28], b3p [2][12]
// wfp [2][100]     : interleaved (Wf_out0[i], Wf_out1[i]) pairs, i = team-local 0..49
#define PRE_OFF   0
#define PRE_TEAM  (170 * 52)                    // 8840
#define W1G_OFF   (2 * PRE_TEAM)                // 17680
#define W2T_OFF   (W1G_OFF + 2 * 52)            // 17784  (x4 B = 71136, 16B-aligned? 71136/16=4446 ✓)
#define W2T_TEAM  (50 * 28)
#define W3T_OFF   (W2T_OFF + 2 * W2T_TEAM)      // 23384
#define W3T_TEAM  (25 * 12)
#define B2P_OFF   (W3T_OFF + 2 * W3T_TEAM)      // 23984
#define B3P_OFF   (B2P_OFF + 2 * 28)            // 24040
#define WFP_OFF   (B3P_OFF + 2 * 12)            // 24064
#define WS_FLOATS (WFP_OFF + 2 * 100)           // 24264 floats = 97056 B

__global__ void precompute(const float* __restrict__ emb,
                           const float* __restrict__ W1a, const float* __restrict__ b1a,
                           const float* __restrict__ W2a, const float* __restrict__ b2a,
                           const float* __restrict__ W3a, const float* __restrict__ b3a,
                           const float* __restrict__ W1b, const float* __restrict__ b1b,
                           const float* __restrict__ W2b, const float* __restrict__ b2b,
                           const float* __restrict__ W3b, const float* __restrict__ b3b,
                           const float* __restrict__ Wf,
                           float* __restrict__ ws)
{
    const int team = blockIdx.y;
    const float* __restrict__ W1 = team ? W1b : W1a;
    const float* __restrict__ B1 = team ? b1b : b1a;
    const float* __restrict__ W2 = team ? W2b : W2a;
    const float* __restrict__ B2 = team ? b2b : b2a;
    const float* __restrict__ W3 = team ? W3b : W3a;
    const float* __restrict__ B3 = team ? b3b : b3a;
    const int tid = threadIdx.x;

    if (blockIdx.x < 170) {
        const int c = blockIdx.x;
        float* prow = ws + PRE_OFF + team * PRE_TEAM + c * 52;
        if (tid < 52) {
            float acc = 0.0f;
            if (tid < 50) {
                acc = B1[tid];
                for (int k = 0; k < 50; ++k)
                    acc = fmaf(W1[tid * 51 + k], emb[c * 50 + k], acc);
            }
            prow[tid] = acc;
        }
    } else {
        float* w1g = ws + W1G_OFF + team * 52;
        for (int i = tid; i < 52; i += 64)
            w1g[i] = (i < 50) ? W1[i * 51 + 50] : 0.0f;
        float* w2t = ws + W2T_OFF + team * W2T_TEAM;
        for (int i = tid; i < 50 * 28; i += 64) {
            int j = i / 28, m = i - j * 28;
            w2t[i] = (m < 25) ? W2[m * 50 + j] : 0.0f;
        }
        float* w3t = ws + W3T_OFF + team * W3T_TEAM;
        for (int i = tid; i < 25 * 12; i += 64) {
            int mm = i / 12, t = i - mm * 12;
            w3t[i] = (t < 10) ? W3[t * 25 + mm] : 0.0f;
        }
        float* b2p = ws + B2P_OFF + team * 28;
        for (int i = tid; i < 28; i += 64) b2p[i] = (i < 25) ? B2[i] : 0.0f;
        float* b3p = ws + B3P_OFF + team * 12;
        for (int i = tid; i < 12; i += 64) b3p[i] = (i < 10) ? B3[i] : 0.0f;
        float* wfp = ws + WFP_OFF + team * 100;
        for (int i = tid; i < 50; i += 64) {
            wfp[2 * i]     = Wf[team * 50 + i];        // -> out0
            wfp[2 * i + 1] = Wf[100 + team * 50 + i];  // -> out1
        }
    }
}

__device__ __forceinline__ v2f bc(float x) { return (v2f){x, x}; }
__device__ __forceinline__ v2f vfma(v2f a, v2f b, v2f c) {
    return __builtin_elementwise_fma(a, b, c);
}
__device__ __forceinline__ v2f vmax0(v2f a) {
    return __builtin_elementwise_max(a, (v2f){0.0f, 0.0f});
}

// Waves 0-1: team A for samples [base, base+128); waves 2-3: team B.
// team is wave-uniform -> every weight-table base stays scalar (s_load).
// All inner loops on float2 ext-vectors -> v_pk_fma_f32 / v_pk_max_f32:
// same fp32 FLOPs, ~1.7x fewer VALU instructions than round 3.
__global__ __launch_bounds__(TPB)
__attribute__((amdgpu_waves_per_eu(4, 8)))
void match_predict(const float* __restrict__ feat, const float* __restrict__ ws,
                   const float* __restrict__ bf,
                   float* __restrict__ out, int nB)
{
    __shared__ float2 part[128];
    const int tid  = threadIdx.x;
    const int sidx = tid & 127;
    const int team = __builtin_amdgcn_readfirstlane(tid >> 7);

    const int s = blockIdx.x * 128 + sidx;
    const bool active = s < nB;

    v2f outp = (v2f){0.0f, 0.0f};   // (out0, out1) partial for this team

    if (active) {
        const float4* f4 = reinterpret_cast<const float4*>(feat + (size_t)s * 12);
        const float4 v0 = f4[0], v1 = f4[1], v2 = f4[2];
        const float fr[12] = {v0.x, v0.y, v0.z, v0.w, v1.x, v1.y, v1.z, v1.w,
                              v2.x, v2.y, v2.z, v2.w};
        const v2f glp = bc(team ? fr[1] : fr[0]);
        int ci[5];
        #pragma unroll
        for (int c = 0; c < 5; ++c)
            ci[c] = (int)(team ? fr[7 + c] : fr[2 + c]);

        const float* __restrict__ pre  = ws + PRE_OFF + team * PRE_TEAM;
        const v2f*   __restrict__ w1gp = (const v2f*)(ws + W1G_OFF + team * 52);
        const v2f*   __restrict__ w2tv = (const v2f*)(ws + W2T_OFF + team * W2T_TEAM);
        const v2f*   __restrict__ w3tv = (const v2f*)(ws + W3T_OFF + team * W3T_TEAM);
        const v2f*   __restrict__ b2pv = (const v2f*)(ws + B2P_OFF + team * 28);
        const v2f*   __restrict__ b3pv = (const v2f*)(ws + B3P_OFF + team * 12);
        const v2f*   __restrict__ wfpv = (const v2f*)(ws + WFP_OFF + team * 100);

        #pragma clang loop unroll(disable)
        for (int c = 0; c < 5; ++c) {
            const float4* prow = reinterpret_cast<const float4*>(pre + ci[c] * 52);

            v2f h2p[14];                       // h2 accumulator, b2 folded in
            #pragma unroll
            for (int q = 0; q < 14; ++q) h2p[q] = b2pv[q];

            // Layer-1 glicko residual + relu, cascaded with layer-2 accumulation.
            #pragma unroll
            for (int jp = 0; jp < 25; ++jp) {  // pair of j's per iteration
                const float4 pq = prow[jp >> 1];
                const v2f pcp = (jp & 1) ? (v2f){pq.z, pq.w} : (v2f){pq.x, pq.y};
                const v2f h1p = vmax0(vfma(w1gp[jp], glp, pcp));
                const v2f blo = bc(h1p.x), bhi = bc(h1p.y);
                const v2f* __restrict__ w2r0 = w2tv + (2 * jp) * 14;
                const v2f* __restrict__ w2r1 = w2r0 + 14;
                #pragma unroll
                for (int q = 0; q < 14; ++q) {
                    h2p[q] = vfma(w2r0[q], blo, h2p[q]);
                    h2p[q] = vfma(w2r1[q], bhi, h2p[q]);
                }
            }

            // Layer 3 (25 -> 10)
            v2f h3p[5];
            #pragma unroll
            for (int t = 0; t < 5; ++t) h3p[t] = b3pv[t];
            #pragma unroll
            for (int q = 0; q < 12; ++q) {     // m pairs 0..23
                const v2f hm = vmax0(h2p[q]);
                const v2f blo = bc(hm.x), bhi = bc(hm.y);
                const v2f* __restrict__ w3r0 = w3tv + (2 * q) * 6;
                const v2f* __restrict__ w3r1 = w3r0 + 6;
                #pragma unroll
                for (int t = 0; t < 5; ++t) {
                    h3p[t] = vfma(w3r0[t], blo, h3p[t]);
                    h3p[t] = vfma(w3r1[t], bhi, h3p[t]);
                }
            }
            {   // m = 24
                const v2f b24 = bc(fmaxf(h2p[12].x, 0.0f));
                const v2f* __restrict__ w3r = w3tv + 24 * 6;
                #pragma unroll
                for (int t = 0; t < 5; ++t) h3p[t] = vfma(w3r[t], b24, h3p[t]);
            }

            // Final layer partial: outp += (wf0[i], wf1[i]) * relu(h3[i])
            const v2f* __restrict__ wfc = wfpv + c * 10;
            #pragma unroll
            for (int tp = 0; tp < 5; ++tp) {
                const v2f hm = vmax0(h3p[tp]);
                outp = vfma(wfc[2 * tp],     bc(hm.x), outp);
                outp = vfma(wfc[2 * tp + 1], bc(hm.y), outp);
            }
        }
    }

    if (team == 0 && active) part[sidx] = make_float2(outp.x, outp.y);
    __syncthreads();
    if (team == 1 && active) {
        const float2 p = part[sidx];
        const float2 bfv = *reinterpret_cast<const float2*>(bf);
        reinterpret_cast<float2*>(out)[s] =
            make_float2(p.x + outp.x + bfv.x, p.y + outp.y + bfv.y);
    }
}

extern "C" void kernel_launch(void* const* d_in, const int* in_sizes, int n_in,
                              void* d_out, int out_size, void* d_ws, size_t ws_size,
                              hipStream_t stream) {
    const float* feat = (const float*)d_in[0];
    const float* emb  = (const float*)d_in[1];
    const float* W1a  = (const float*)d_in[2];
    const float* b1a  = (const float*)d_in[3];
    const float* W2a  = (const float*)d_in[4];
    const float* b2a  = (const float*)d_in[5];
    const float* W3a  = (const float*)d_in[6];
    const float* b3a  = (const float*)d_in[7];
    const float* W1b  = (const float*)d_in[8];
    const float* b1b  = (const float*)d_in[9];
    const float* W2b  = (const float*)d_in[10];
    const float* b2b  = (const float*)d_in[11];
    const float* W3b  = (const float*)d_in[12];
    const float* b3b  = (const float*)d_in[13];
    const float* Wf   = (const float*)d_in[14];
    const float* bf   = (const float*)d_in[15];
    float* out = (float*)d_out;
    float* ws  = (float*)d_ws;

    const int nB = in_sizes[0] / 12;

    precompute<<<dim3(171, 2), 64, 0, stream>>>(emb,
        W1a, b1a, W2a, b2a, W3a, b3a,
        W1b, b1b, W2b, b2b, W3b, b3b, Wf, ws);

    const int blocks = (nB + 127) / 128;
    match_predict<<<blocks, TPB, 0, stream>>>(feat, ws, bf, out, nB);
}

// Round 5
// 129.312 us; speedup vs baseline: 1.8118x; 1.8118x over previous
//
#include <hip/hip_runtime.h>

typedef _Float16 f16x8 __attribute__((ext_vector_type(8)));
typedef float    f32x4 __attribute__((ext_vector_type(4)));

// ---- workspace layout ----
// halfword section (index in _Float16 units from ws base):
//   pre16 [2][170][64] : f16(W1[:, :50] @ emb + b1), k-padded 50->64 with 0
//   w1g   [2][64]      : f16 glicko column of W1, padded 0
//   w2p   [2][32][64]  : f16 W2 rows (out m=0..24, pad to 32) x k (0..49 pad 64)
//   w3p   [2][16][32]  : f16 W3 rows (out t=0..9, pad 16) x m (0..24 pad 32)
// float section at FOFF halfwords (8B aligned):
//   b2p [2][32], b3p [2][16], wfp [2][5][16][2]  (pads 0)
#define PRE_OFF   0
#define PRE_SZ    (2 * 170 * 64)              // 21760
#define W1G_OFF   (PRE_OFF + PRE_SZ)
#define W2P_OFF   (W1G_OFF + 2 * 64)          // 21888
#define W3P_OFF   (W2P_OFF + 2 * 32 * 64)     // 25984
#define H16_END   (W3P_OFF + 2 * 16 * 32)     // 27008
#define FOFF      ((H16_END + 3) & ~3)        // 27008 (x2B = 54016, 8B-aligned)
#define B2P_F     0
#define B3P_F     (B2P_F + 2 * 32)
#define WFP_F     (B3P_F + 2 * 16)            // [ (team*5+slot)*16 + col ][2]

__global__ void precompute(const float* __restrict__ emb,
                           const float* __restrict__ W1a, const float* __restrict__ b1a,
                           const float* __restrict__ W2a, const float* __restrict__ b2a,
                           const float* __restrict__ W3a, const float* __restrict__ b3a,
                           const float* __restrict__ W1b, const float* __restrict__ b1b,
                           const float* __restrict__ W2b, const float* __restrict__ b2b,
                           const float* __restrict__ W3b, const float* __restrict__ b3b,
                           const float* __restrict__ Wf,
                           _Float16* __restrict__ ws16)
{
    const int team = blockIdx.x;
    const float* __restrict__ W1 = team ? W1b : W1a;
    const float* __restrict__ B1 = team ? b1b : b1a;
    const float* __restrict__ W2 = team ? W2b : W2a;
    const float* __restrict__ B2 = team ? b2b : b2a;
    const float* __restrict__ W3 = team ? W3b : W3a;
    const float* __restrict__ B3 = team ? b3b : b3a;
    float* __restrict__ wsf = (float*)(ws16 + FOFF);
    const int tid = threadIdx.x;

    for (int i = tid; i < 170 * 64; i += 256) {
        const int c = i >> 6, k = i & 63;
        float v = 0.0f;
        if (k < 50) {
            v = B1[k];
            for (int d = 0; d < 50; ++d)
                v = fmaf(W1[k * 51 + d], emb[c * 50 + d], v);
        }
        ws16[PRE_OFF + team * 170 * 64 + i] = (_Float16)v;
    }
    for (int i = tid; i < 64; i += 256)
        ws16[W1G_OFF + team * 64 + i] = (_Float16)((i < 50) ? W1[i * 51 + 50] : 0.0f);
    for (int i = tid; i < 32 * 64; i += 256) {
        const int m = i >> 6, k = i & 63;
        ws16[W2P_OFF + team * 2048 + i] =
            (_Float16)((m < 25 && k < 50) ? W2[m * 50 + k] : 0.0f);
    }
    for (int i = tid; i < 16 * 32; i += 256) {
        const int t = i >> 5, m = i & 31;
        ws16[W3P_OFF + team * 512 + i] =
            (_Float16)((t < 10 && m < 25) ? W3[t * 25 + m] : 0.0f);
    }
    for (int i = tid; i < 32; i += 256) wsf[B2P_F + team * 32 + i] = (i < 25) ? B2[i] : 0.0f;
    for (int i = tid; i < 16; i += 256) wsf[B3P_F + team * 16 + i] = (i < 10) ? B3[i] : 0.0f;
    for (int i = tid; i < 5 * 16; i += 256) {
        const int s = i >> 4, cc = i & 15;
        const int o = (team * 5 + s) * 16 + cc;
        wsf[WFP_F + 2 * o + 0] = (cc < 10) ? Wf[team * 50 + s * 10 + cc] : 0.0f;
        wsf[WFP_F + 2 * o + 1] = (cc < 10) ? Wf[100 + team * 50 + s * 10 + cc] : 0.0f;
    }
}

__device__ __forceinline__ f16x8 hfma8(f16x8 a, f16x8 b, f16x8 c) {
    return __builtin_elementwise_fma(a, b, c);
}
__device__ __forceinline__ f16x8 hrelu8(f16x8 a) {
    const f16x8 z = {0, 0, 0, 0, 0, 0, 0, 0};
    return __builtin_elementwise_max(a, z);
}

// One wave owns 16 consecutive samples. Per champion-slot (10): build the
// h1 A-fragment from per-lane gathers of the f16 pre-table (lane&15 = sample
// row, lane>>4 = k-chunk), 4 MFMAs for layer 2 (N=25 -> 2 tiles, K=64),
// round-trip h2 through WAVE-PRIVATE LDS to re-fragment, 1 MFMA for layer 3,
// accumulate the final layer per-lane; one 4-step shfl_xor reduce per wave.
// No __syncthreads anywhere (all LDS producer/consumer is intra-wave).
__global__ __launch_bounds__(256)
__attribute__((amdgpu_waves_per_eu(4, 4)))
void match_predict(const float* __restrict__ feat, const _Float16* __restrict__ ws16,
                   const float* __restrict__ bf, float* __restrict__ out, int nB)
{
    __shared__ __align__(16) _Float16 h2buf[4][640];   // [wave][16 rows x 40 (25 pad)]
    const int tid = threadIdx.x;
    const int wv = tid >> 6;
    const int l  = tid & 63;
    const int c  = l & 15;          // sample-row / output-col index
    const int g  = l >> 4;          // k-chunk group
    const float* __restrict__ wsf = (const float*)(ws16 + FOFF);

    const int base = (blockIdx.x * 4 + wv) * 16;
    if (base >= nB) return;
    const int sample = base + c;
    const int sEff   = (sample < nB) ? sample : (nB - 1);
    _Float16* __restrict__ h2b = h2buf[wv];

    float accO[4][2];
    #pragma unroll
    for (int q = 0; q < 4; ++q) { accO[q][0] = 0.0f; accO[q][1] = 0.0f; }

    #pragma clang loop unroll(disable)
    for (int team = 0; team < 2; ++team) {
        const _Float16* __restrict__ preb = ws16 + PRE_OFF + team * 170 * 64;
        const _Float16* __restrict__ w1p  = ws16 + W1G_OFF + team * 64;
        const _Float16* __restrict__ w2p  = ws16 + W2P_OFF + team * 2048;
        const _Float16* __restrict__ w3p  = ws16 + W3P_OFF + team * 512;

        // B fragments: lane supplies B[k=(g)*8+i][col=c] = W[row=c][k] (contig k)
        f16x8 w2f[2][2];
        #pragma unroll
        for (int nt = 0; nt < 2; ++nt)
            #pragma unroll
            for (int kf = 0; kf < 2; ++kf)
                w2f[nt][kf] = *(const f16x8*)(w2p + (nt * 16 + c) * 64 + kf * 32 + g * 8);
        const f16x8 w3f    = *(const f16x8*)(w3p + c * 32 + g * 8);
        const f16x8 w1gf0  = *(const f16x8*)(w1p + g * 8);
        const f16x8 w1gf1  = *(const f16x8*)(w1p + 32 + g * 8);

        const float b2lo = wsf[B2P_F + team * 32 + c];
        const float b2hi = wsf[B2P_F + team * 32 + 16 + c];
        const float b3v  = wsf[B3P_F + team * 16 + c];

        const _Float16 glh = (_Float16)feat[(size_t)sEff * 12 + team];
        const f16x8 glv = {glh, glh, glh, glh, glh, glh, glh, glh};

        #pragma clang loop unroll(disable)
        for (int s5 = 0; s5 < 5; ++s5) {
            const int ci = (int)feat[(size_t)sEff * 12 + 2 + team * 5 + s5];
            const _Float16* __restrict__ prow = preb + ci * 64;

            // A fragments: h1[row=c][k=g*8+i]
            const f16x8 pa0 = *(const f16x8*)(prow + g * 8);
            const f16x8 pa1 = *(const f16x8*)(prow + 32 + g * 8);
            const f16x8 h10 = hrelu8(hfma8(w1gf0, glv, pa0));
            const f16x8 h11 = hrelu8(hfma8(w1gf1, glv, pa1));

            // Layer 2: h2[16 rows][32 cols] in two N-tiles, K = 64
            f32x4 acc0 = {0.f, 0.f, 0.f, 0.f}, acc1 = {0.f, 0.f, 0.f, 0.f};
            acc0 = __builtin_amdgcn_mfma_f32_16x16x32_f16(h10, w2f[0][0], acc0, 0, 0, 0);
            acc0 = __builtin_amdgcn_mfma_f32_16x16x32_f16(h11, w2f[0][1], acc0, 0, 0, 0);
            acc1 = __builtin_amdgcn_mfma_f32_16x16x32_f16(h10, w2f[1][0], acc1, 0, 0, 0);
            acc1 = __builtin_amdgcn_mfma_f32_16x16x32_f16(h11, w2f[1][1], acc1, 0, 0, 0);

            // Epilogue: +b2, relu, cvt f16, stage to wave-private LDS.
            // C layout: lane holds rows 4g+q, col c (ntile0) / 16+c (ntile1).
            #pragma unroll
            for (int q = 0; q < 4; ++q) {
                const int row = g * 4 + q;
                h2b[row * 40 + c]      = (_Float16)fmaxf(acc0[q] + b2lo, 0.0f);
                h2b[row * 40 + 16 + c] = (_Float16)fmaxf(acc1[q] + b2hi, 0.0f);
            }

            // Layer 3 A-fragment: h2[row=c][k=g*8+i]  (k 25..31 are zero pads)
            const f16x8 a3 = *(const f16x8*)(h2b + c * 40 + g * 8);
            f32x4 acc3 = {0.f, 0.f, 0.f, 0.f};
            acc3 = __builtin_amdgcn_mfma_f32_16x16x32_f16(a3, w3f, acc3, 0, 0, 0);

            // Final layer partial: lane holds h3[rows 4g+q][t=c]
            const float* __restrict__ wfp = wsf + WFP_F + 2 * ((team * 5 + s5) * 16 + c);
            const float wf0 = wfp[0], wf1 = wfp[1];
            #pragma unroll
            for (int q = 0; q < 4; ++q) {
                const float h3 = fmaxf(acc3[q] + b3v, 0.0f);
                accO[q][0] = fmaf(h3, wf0, accO[q][0]);
                accO[q][1] = fmaf(h3, wf1, accO[q][1]);
            }
        }
    }

    // Reduce over the 16 t-columns (lanes sharing g)
    #pragma unroll
    for (int st = 1; st < 16; st <<= 1) {
        #pragma unroll
        for (int q = 0; q < 4; ++q) {
            accO[q][0] += __shfl_xor(accO[q][0], st, 64);
            accO[q][1] += __shfl_xor(accO[q][1], st, 64);
        }
    }
    if (c == 0) {
        const float bf0 = bf[0], bf1 = bf[1];
        #pragma unroll
        for (int q = 0; q < 4; ++q) {
            const int s = base + g * 4 + q;
            if (s < nB)
                reinterpret_cast<float2*>(out)[s] =
                    make_float2(accO[q][0] + bf0, accO[q][1] + bf1);
        }
    }
}

extern "C" void kernel_launch(void* const* d_in, const int* in_sizes, int n_in,
                              void* d_out, int out_size, void* d_ws, size_t ws_size,
                              hipStream_t stream) {
    const float* feat = (const float*)d_in[0];
    const float* emb  = (const float*)d_in[1];
    const float* W1a  = (const float*)d_in[2];
    const float* b1a  = (const float*)d_in[3];
    const float* W2a  = (const float*)d_in[4];
    const float* b2a  = (const float*)d_in[5];
    const float* W3a  = (const float*)d_in[6];
    const float* b3a  = (const float*)d_in[7];
    const float* W1b  = (const float*)d_in[8];
    const float* b1b  = (const float*)d_in[9];
    const float* W2b  = (const float*)d_in[10];
    const float* b2b  = (const float*)d_in[11];
    const float* W3b  = (const float*)d_in[12];
    const float* b3b  = (const float*)d_in[13];
    const float* Wf   = (const float*)d_in[14];
    const float* bf   = (const float*)d_in[15];
    float* out = (float*)d_out;
    _Float16* ws16 = (_Float16*)d_ws;

    const int nB = in_sizes[0] / 12;

    precompute<<<dim3(2), 256, 0, stream>>>(emb,
        W1a, b1a, W2a, b2a, W3a, b3a,
        W1b, b1b, W2b, b2b, W3b, b3b, Wf, ws16);

    const int blocks = (nB + 63) / 64;
    match_predict<<<blocks, 256, 0, stream>>>(feat, ws16, bf, out, nB);
}

// Round 6
// 83.143 us; speedup vs baseline: 2.8179x; 1.5553x over previous
//
#include <hip/hip_runtime.h>

typedef _Float16 f16x8 __attribute__((ext_vector_type(8)));
typedef _Float16 f16x2 __attribute__((ext_vector_type(2)));
typedef float    f32x4 __attribute__((ext_vector_type(4)));

// ---- workspace layout (halfword units from ws base) ----
//   pre16 [2][170][64] : f16(W1[:, :50] @ emb + b1), k-padded 50->64 with 0
//   w1g   [2][64]      : f16 glicko column of W1, padded 0
//   w2p   [2][32][64]  : f16 W2 rows (m=0..24, pad 32) x k (0..49, pad 64)
//   w3p   [2][16][32]  : f16 W3 rows (t=0..9, pad 16) x m (0..24, pad 32)
// float section at FOFF halfwords:
//   b2p [2][32], b3p [2][16], wfp [2][5][16][2]  (pads 0)
#define PRE_OFF   0
#define PRE_SZ    (2 * 170 * 64)
#define W1G_OFF   (PRE_OFF + PRE_SZ)          // 21760
#define W2P_OFF   (W1G_OFF + 2 * 64)          // 21888
#define W3P_OFF   (W2P_OFF + 2 * 32 * 64)     // 25984
#define H16_END   (W3P_OFF + 2 * 16 * 32)     // 27008
#define FOFF      ((H16_END + 3) & ~3)        // 27008
#define B2P_F     0
#define B3P_F     (B2P_F + 2 * 32)            // 64
#define WFP_F     (B3P_F + 2 * 16)            // 96

__global__ void precompute(const float* __restrict__ emb,
                           const float* __restrict__ W1a, const float* __restrict__ b1a,
                           const float* __restrict__ W2a, const float* __restrict__ b2a,
                           const float* __restrict__ W3a, const float* __restrict__ b3a,
                           const float* __restrict__ W1b, const float* __restrict__ b1b,
                           const float* __restrict__ W2b, const float* __restrict__ b2b,
                           const float* __restrict__ W3b, const float* __restrict__ b3b,
                           const float* __restrict__ Wf,
                           _Float16* __restrict__ ws16)
{
    const int team = blockIdx.y;
    const float* __restrict__ W1 = team ? W1b : W1a;
    const float* __restrict__ B1 = team ? b1b : b1a;
    const float* __restrict__ W2 = team ? W2b : W2a;
    const float* __restrict__ B2 = team ? b2b : b2a;
    const float* __restrict__ W3 = team ? W3b : W3a;
    const float* __restrict__ B3 = team ? b3b : b3a;
    float* __restrict__ wsf = (float*)(ws16 + FOFF);
    const int tid = threadIdx.x;

    if (blockIdx.x < 170) {
        const int cc = blockIdx.x;
        const int k = tid;   // 64 threads, one output each
        float v = 0.0f;
        if (k < 50) {
            v = B1[k];
            for (int d = 0; d < 50; ++d)
                v = fmaf(W1[k * 51 + d], emb[cc * 50 + d], v);
        }
        ws16[PRE_OFF + team * 170 * 64 + cc * 64 + k] = (_Float16)v;
    } else {
        for (int i = tid; i < 64; i += 64)
            ws16[W1G_OFF + team * 64 + i] = (_Float16)((i < 50) ? W1[i * 51 + 50] : 0.0f);
        for (int i = tid; i < 32 * 64; i += 64) {
            const int m = i >> 6, k = i & 63;
            ws16[W2P_OFF + team * 2048 + i] =
                (_Float16)((m < 25 && k < 50) ? W2[m * 50 + k] : 0.0f);
        }
        for (int i = tid; i < 16 * 32; i += 64) {
            const int t = i >> 5, m = i & 31;
            ws16[W3P_OFF + team * 512 + i] =
                (_Float16)((t < 10 && m < 25) ? W3[t * 25 + m] : 0.0f);
        }
        for (int i = tid; i < 32; i += 64) wsf[B2P_F + team * 32 + i] = (i < 25) ? B2[i] : 0.0f;
        for (int i = tid; i < 16; i += 64) wsf[B3P_F + team * 16 + i] = (i < 10) ? B3[i] : 0.0f;
        for (int i = tid; i < 5 * 16; i += 64) {
            const int s = i >> 4, cc2 = i & 15;
            const int o = (team * 5 + s) * 16 + cc2;
            wsf[WFP_F + 2 * o + 0] = (cc2 < 10) ? Wf[team * 50 + s * 10 + cc2] : 0.0f;
            wsf[WFP_F + 2 * o + 1] = (cc2 < 10) ? Wf[100 + team * 50 + s * 10 + cc2] : 0.0f;
        }
    }
}

__device__ __forceinline__ f16x8 hfma8(f16x8 a, f16x8 b, f16x8 c) {
    return __builtin_elementwise_fma(a, b, c);
}
__device__ __forceinline__ f16x8 hrelu8(f16x8 a) {
    const f16x8 z = {0, 0, 0, 0, 0, 0, 0, 0};
    return __builtin_elementwise_max(a, z);
}
__device__ __forceinline__ int pack2(float a, float b) {
    f16x2 p;
    p.x = (_Float16)a;
    p.y = (_Float16)b;
    return __builtin_bit_cast(int, p);
}

// One wave owns 16 samples. Operand-swapped MFMAs keep the sample index in the
// C COLUMN through both layers:
//   layer2: h2^T = W2 . h1^T  (A = W2-frag, B = h1^T-frag, Cin = b2)
//   layer3: h3^T = W3 . h2^T  (A = W3-frag, B = shuffled h2^T, Cin = b3)
// The h2^T -> B-frag redistribution stays within the 4 lanes sharing column c:
// 8 __shfl + 4 selects + 4 f16 packs, all in-register. No LDS, no barriers.
__global__ __launch_bounds__(256)
__attribute__((amdgpu_waves_per_eu(2, 8)))
void match_predict(const float* __restrict__ feat, const _Float16* __restrict__ ws16,
                   const float* __restrict__ bf, float* __restrict__ out, int nB)
{
    const int tid = threadIdx.x;
    const int l  = tid & 63;
    const int c  = l & 15;          // sample column
    const int g  = l >> 4;          // k-chunk / row group
    const int wv = tid >> 6;
    const float* __restrict__ wsf = (const float*)(ws16 + FOFF);

    const int base = (blockIdx.x * 4 + wv) * 16;
    if (base >= nB) return;
    const int sample = base + c;
    const int sEff   = (sample < nB) ? sample : (nB - 1);

    // 12 features of this lane's sample (static-indexed only)
    const float4* f4 = reinterpret_cast<const float4*>(feat + (size_t)sEff * 12);
    const float4 v0 = f4[0], v1 = f4[1], v2 = f4[2];
    const float fr[12] = {v0.x, v0.y, v0.z, v0.w, v1.x, v1.y, v1.z, v1.w,
                          v2.x, v2.y, v2.z, v2.w};

    const int srcA = c + 16 * ((2 * g) & 3);
    const int srcB = c + 16 * ((2 * g + 1) & 3);
    const bool low = (g < 2);

    float accO0 = 0.0f, accO1 = 0.0f;

    #pragma unroll
    for (int team = 0; team < 2; ++team) {
        const _Float16* __restrict__ preb = ws16 + PRE_OFF + team * 170 * 64;
        const _Float16* __restrict__ w1p  = ws16 + W1G_OFF + team * 64;
        const _Float16* __restrict__ w2p  = ws16 + W2P_OFF + team * 2048;
        const _Float16* __restrict__ w3p  = ws16 + W3P_OFF + team * 512;

        // A-frags (sample-independent): W2 rows (2 M-tiles x 2 K-chunks), W3 row
        f16x8 w2A[2][2];
        #pragma unroll
        for (int mt = 0; mt < 2; ++mt)
            #pragma unroll
            for (int kf = 0; kf < 2; ++kf)
                w2A[mt][kf] = *(const f16x8*)(w2p + (mt * 16 + c) * 64 + kf * 32 + g * 8);
        const f16x8 w3A   = *(const f16x8*)(w3p + c * 32 + g * 8);
        const f16x8 w1gf0 = *(const f16x8*)(w1p + g * 8);
        const f16x8 w1gf1 = *(const f16x8*)(w1p + 32 + g * 8);

        // bias C-in fragments (per-lane f32x4)
        const f32x4 b2v0 = *(const f32x4*)(wsf + B2P_F + team * 32 + 4 * g);
        const f32x4 b2v1 = *(const f32x4*)(wsf + B2P_F + team * 32 + 16 + 4 * g);
        const f32x4 b3v  = *(const f32x4*)(wsf + B3P_F + team * 16 + 4 * g);

        const _Float16 glh = (_Float16)fr[team];
        const f16x8 glv = {glh, glh, glh, glh, glh, glh, glh, glh};

        #pragma unroll
        for (int s5 = 0; s5 < 5; ++s5) {
            const int ci = (int)fr[2 + team * 5 + s5];
            const _Float16* __restrict__ prow = preb + ci * 64;

            // h1^T B-frag: lane supplies h1[sample c][k = chunk*32 + g*8 + i]
            const f16x8 pa0 = *(const f16x8*)(prow + g * 8);
            const f16x8 pa1 = *(const f16x8*)(prow + 32 + g * 8);
            const f16x8 h10 = hrelu8(hfma8(w1gf0, glv, pa0));
            const f16x8 h11 = hrelu8(hfma8(w1gf1, glv, pa1));

            // layer 2: h2^T[m][c], m-tiles {0..15}, {16..31}; b2 folded as C-in
            f32x4 a0 = b2v0, a1 = b2v1;
            a0 = __builtin_amdgcn_mfma_f32_16x16x32_f16(w2A[0][0], h10, a0, 0, 0, 0);
            a0 = __builtin_amdgcn_mfma_f32_16x16x32_f16(w2A[0][1], h11, a0, 0, 0, 0);
            a1 = __builtin_amdgcn_mfma_f32_16x16x32_f16(w2A[1][0], h10, a1, 0, 0, 0);
            a1 = __builtin_amdgcn_mfma_f32_16x16x32_f16(w2A[1][1], h11, a1, 0, 0, 0);

            // relu + pack to f16 pairs: pk{tile}{pair}, lane (c,g') holds m=4g'+q (+16)
            const int pk00 = pack2(fmaxf(a0[0], 0.f), fmaxf(a0[1], 0.f));
            const int pk01 = pack2(fmaxf(a0[2], 0.f), fmaxf(a0[3], 0.f));
            const int pk10 = pack2(fmaxf(a1[0], 0.f), fmaxf(a1[1], 0.f));
            const int pk11 = pack2(fmaxf(a1[2], 0.f), fmaxf(a1[3], 0.f));

            // redistribute -> layer-3 B-frag: lane (c,g) needs m = 8g..8g+7
            const int sA00 = __shfl(pk00, srcA, 64);
            const int sA01 = __shfl(pk01, srcA, 64);
            const int sA10 = __shfl(pk10, srcA, 64);
            const int sA11 = __shfl(pk11, srcA, 64);
            const int sB00 = __shfl(pk00, srcB, 64);
            const int sB01 = __shfl(pk01, srcB, 64);
            const int sB10 = __shfl(pk10, srcB, 64);
            const int sB11 = __shfl(pk11, srcB, 64);

            union { int u[4]; f16x8 v; } bf3;
            bf3.u[0] = low ? sA00 : sA10;
            bf3.u[1] = low ? sA01 : sA11;
            bf3.u[2] = low ? sB00 : sB10;
            bf3.u[3] = low ? sB01 : sB11;

            // layer 3: h3^T[t][c], b3 folded as C-in
            f32x4 a3 = b3v;
            a3 = __builtin_amdgcn_mfma_f32_16x16x32_f16(w3A, bf3.v, a3, 0, 0, 0);

            // final layer: lane holds h3[t = 4g+q][sample c]
            const float* __restrict__ wfb =
                wsf + WFP_F + 2 * ((team * 5 + s5) * 16) + 8 * g;
            const float4 wfA = *(const float4*)(wfb);       // (wf0,wf1) x t=4g,4g+1
            const float4 wfB = *(const float4*)(wfb + 4);   // (wf0,wf1) x t=4g+2,4g+3
            const float h30 = fmaxf(a3[0], 0.f);
            const float h31 = fmaxf(a3[1], 0.f);
            const float h32 = fmaxf(a3[2], 0.f);
            const float h33 = fmaxf(a3[3], 0.f);
            accO0 = fmaf(wfA.x, h30, accO0);
            accO1 = fmaf(wfA.y, h30, accO1);
            accO0 = fmaf(wfA.z, h31, accO0);
            accO1 = fmaf(wfA.w, h31, accO1);
            accO0 = fmaf(wfB.x, h32, accO0);
            accO1 = fmaf(wfB.y, h32, accO1);
            accO0 = fmaf(wfB.z, h33, accO0);
            accO1 = fmaf(wfB.w, h33, accO1);
        }
    }

    // reduce over the 4 row-groups sharing column c
    accO0 += __shfl_xor(accO0, 16, 64);
    accO0 += __shfl_xor(accO0, 32, 64);
    accO1 += __shfl_xor(accO1, 16, 64);
    accO1 += __shfl_xor(accO1, 32, 64);

    if (l < 16 && sample < nB) {
        reinterpret_cast<float2*>(out)[sample] =
            make_float2(accO0 + bf[0], accO1 + bf[1]);
    }
}

extern "C" void kernel_launch(void* const* d_in, const int* in_sizes, int n_in,
                              void* d_out, int out_size, void* d_ws, size_t ws_size,
                              hipStream_t stream) {
    const float* feat = (const float*)d_in[0];
    const float* emb  = (const float*)d_in[1];
    const float* W1a  = (const float*)d_in[2];
    const float* b1a  = (const float*)d_in[3];
    const float* W2a  = (const float*)d_in[4];
    const float* b2a  = (const float*)d_in[5];
    const float* W3a  = (const float*)d_in[6];
    const float* b3a  = (const float*)d_in[7];
    const float* W1b  = (const float*)d_in[8];
    const float* b1b  = (const float*)d_in[9];
    const float* W2b  = (const float*)d_in[10];
    const float* b2b  = (const float*)d_in[11];
    const float* W3b  = (const float*)d_in[12];
    const float* b3b  = (const float*)d_in[13];
    const float* Wf   = (const float*)d_in[14];
    const float* bf   = (const float*)d_in[15];
    float* out = (float*)d_out;
    _Float16* ws16 = (_Float16*)d_ws;

    const int nB = in_sizes[0] / 12;

    precompute<<<dim3(171, 2), 64, 0, stream>>>(emb,
        W1a, b1a, W2a, b2a, W3a, b3a,
        W1b, b1b, W2b, b2b, W3b, b3b, Wf, ws16);

    const int blocks = (nB + 63) / 64;
    match_predict<<<blocks, 256, 0, stream>>>(feat, ws16, bf, out, nB);
}

// Round 7
// 80.453 us; speedup vs baseline: 2.9122x; 1.0334x over previous
//
#include <hip/hip_runtime.h>

typedef _Float16 f16x8 __attribute__((ext_vector_type(8)));
typedef _Float16 f16x2 __attribute__((ext_vector_type(2)));
typedef float    f32x4 __attribute__((ext_vector_type(4)));

// ---- workspace layout (halfword units from ws base) ----
//   pre16 [2][170][64] : f16(W1[:, :50] @ emb + b1), k-padded 50->64 with 0
//   w1g   [2][64]      : f16 glicko column of W1, padded 0
//   w2p   [2][32][64]  : f16 W2 rows (m=0..24, pad 32) x k (0..49, pad 64)
//   w3p   [2][16][32]  : f16 W3 rows (t=0..9, pad 16) x m (0..24, pad 32)
// float section at FOFF halfwords:
//   b2p [2][32], b3p [2][16], wfp [2][5][16][2]  (pads 0)
#define PRE_OFF   0
#define PRE_SZ    (2 * 170 * 64)
#define W1G_OFF   (PRE_OFF + PRE_SZ)          // 21760
#define W2P_OFF   (W1G_OFF + 2 * 64)          // 21888
#define W3P_OFF   (W2P_OFF + 2 * 32 * 64)     // 25984
#define H16_END   (W3P_OFF + 2 * 16 * 32)     // 27008
#define FOFF      ((H16_END + 3) & ~3)        // 27008
#define B2P_F     0
#define B3P_F     (B2P_F + 2 * 32)            // 64
#define WFP_F     (B3P_F + 2 * 16)            // 96

__global__ void precompute(const float* __restrict__ emb,
                           const float* __restrict__ W1a, const float* __restrict__ b1a,
                           const float* __restrict__ W2a, const float* __restrict__ b2a,
                           const float* __restrict__ W3a, const float* __restrict__ b3a,
                           const float* __restrict__ W1b, const float* __restrict__ b1b,
                           const float* __restrict__ W2b, const float* __restrict__ b2b,
                           const float* __restrict__ W3b, const float* __restrict__ b3b,
                           const float* __restrict__ Wf,
                           _Float16* __restrict__ ws16)
{
    const int team = blockIdx.y;
    const float* __restrict__ W1 = team ? W1b : W1a;
    const float* __restrict__ B1 = team ? b1b : b1a;
    const float* __restrict__ W2 = team ? W2b : W2a;
    const float* __restrict__ B2 = team ? b2b : b2a;
    const float* __restrict__ W3 = team ? W3b : W3a;
    const float* __restrict__ B3 = team ? b3b : b3a;
    float* __restrict__ wsf = (float*)(ws16 + FOFF);
    const int tid = threadIdx.x;

    if (blockIdx.x < 170) {
        const int cc = blockIdx.x;
        const int k = tid;   // 64 threads, one output each
        float v = 0.0f;
        if (k < 50) {
            v = B1[k];
            for (int d = 0; d < 50; ++d)
                v = fmaf(W1[k * 51 + d], emb[cc * 50 + d], v);
        }
        ws16[PRE_OFF + team * 170 * 64 + cc * 64 + k] = (_Float16)v;
    } else {
        for (int i = tid; i < 64; i += 64)
            ws16[W1G_OFF + team * 64 + i] = (_Float16)((i < 50) ? W1[i * 51 + 50] : 0.0f);
        for (int i = tid; i < 32 * 64; i += 64) {
            const int m = i >> 6, k = i & 63;
            ws16[W2P_OFF + team * 2048 + i] =
                (_Float16)((m < 25 && k < 50) ? W2[m * 50 + k] : 0.0f);
        }
        for (int i = tid; i < 16 * 32; i += 64) {
            const int t = i >> 5, m = i & 31;
            ws16[W3P_OFF + team * 512 + i] =
                (_Float16)((t < 10 && m < 25) ? W3[t * 25 + m] : 0.0f);
        }
        for (int i = tid; i < 32; i += 64) wsf[B2P_F + team * 32 + i] = (i < 25) ? B2[i] : 0.0f;
        for (int i = tid; i < 16; i += 64) wsf[B3P_F + team * 16 + i] = (i < 10) ? B3[i] : 0.0f;
        for (int i = tid; i < 5 * 16; i += 64) {
            const int s = i >> 4, cc2 = i & 15;
            const int o = (team * 5 + s) * 16 + cc2;
            wsf[WFP_F + 2 * o + 0] = (cc2 < 10) ? Wf[team * 50 + s * 10 + cc2] : 0.0f;
            wsf[WFP_F + 2 * o + 1] = (cc2 < 10) ? Wf[100 + team * 50 + s * 10 + cc2] : 0.0f;
        }
    }
}

__device__ __forceinline__ f16x8 hfma8(f16x8 a, f16x8 b, f16x8 c) {
    return __builtin_elementwise_fma(a, b, c);
}
__device__ __forceinline__ f16x8 hrelu8(f16x8 a) {
    const f16x8 z = {0, 0, 0, 0, 0, 0, 0, 0};
    return __builtin_elementwise_max(a, z);
}
__device__ __forceinline__ int pack2(float a, float b) {
    f16x2 p;
    p.x = (_Float16)a;
    p.y = (_Float16)b;
    return __builtin_bit_cast(int, p);
}

// One wave = 16 samples, operand-swapped MFMAs (sample stays in C column).
// Round-7 restructure: explicit PREFETCH phase pulls all 20 pre-table gathers
// plus every weight/bias fragment into registers BEFORE any compute (one
// latency wall), then 10 independent slot chains run back-to-back out of
// registers so the scheduler can interleave them (round-6 failure: per-slot
// serial gather->compute chains, 28K-cycle wave lifetime, 22% VALUBusy).
__global__ __launch_bounds__(256)
__attribute__((amdgpu_waves_per_eu(2, 8)))
void match_predict(const float* __restrict__ feat, const _Float16* __restrict__ ws16,
                   const float* __restrict__ bf, float* __restrict__ out, int nB)
{
    const int tid = threadIdx.x;
    const int l  = tid & 63;
    const int c  = l & 15;          // sample column
    const int g  = l >> 4;          // k-chunk / row group
    const int wv = tid >> 6;
    const float* __restrict__ wsf = (const float*)(ws16 + FOFF);

    const int base = (blockIdx.x * 4 + wv) * 16;
    if (base >= nB) return;
    const int sample = base + c;
    const int sEff   = (sample < nB) ? sample : (nB - 1);

    const float4* f4 = reinterpret_cast<const float4*>(feat + (size_t)sEff * 12);
    const float4 v0 = f4[0], v1 = f4[1], v2 = f4[2];
    const float fr[12] = {v0.x, v0.y, v0.z, v0.w, v1.x, v1.y, v1.z, v1.w,
                          v2.x, v2.y, v2.z, v2.w};

    // ---- prefetch: all 20 pre-row gathers in flight at once ----
    f16x8 pa0[10], pa1[10];
    #pragma unroll
    for (int slot = 0; slot < 10; ++slot) {
        const int team = slot / 5;                 // compile-time after unroll
        const int ci = (int)fr[2 + slot];
        const _Float16* __restrict__ prow =
            ws16 + PRE_OFF + team * (170 * 64) + ci * 64 + g * 8;
        pa0[slot] = *(const f16x8*)(prow);
        pa1[slot] = *(const f16x8*)(prow + 32);
    }

    // ---- weight fragments + biases, both teams ----
    f16x8 w2A[2][2][2];                            // [team][mtile][kchunk]
    f16x8 w3A[2], w1gA[2], w1gB[2], glv[2];
    f32x4 b2lo[2], b2hi[2], b3v[2];
    #pragma unroll
    for (int team = 0; team < 2; ++team) {
        const _Float16* __restrict__ w2p = ws16 + W2P_OFF + team * 2048;
        #pragma unroll
        for (int mt = 0; mt < 2; ++mt)
            #pragma unroll
            for (int kf = 0; kf < 2; ++kf)
                w2A[team][mt][kf] =
                    *(const f16x8*)(w2p + (mt * 16 + c) * 64 + kf * 32 + g * 8);
        w3A[team]  = *(const f16x8*)(ws16 + W3P_OFF + team * 512 + c * 32 + g * 8);
        w1gA[team] = *(const f16x8*)(ws16 + W1G_OFF + team * 64 + g * 8);
        w1gB[team] = *(const f16x8*)(ws16 + W1G_OFF + team * 64 + 32 + g * 8);
        b2lo[team] = *(const f32x4*)(wsf + B2P_F + team * 32 + 4 * g);
        b2hi[team] = *(const f32x4*)(wsf + B2P_F + team * 32 + 16 + 4 * g);
        b3v[team]  = *(const f32x4*)(wsf + B3P_F + team * 16 + 4 * g);
        const _Float16 glh = (_Float16)fr[team];
        glv[team] = (f16x8){glh, glh, glh, glh, glh, glh, glh, glh};
    }

    const int srcA = c + 16 * ((2 * g) & 3);
    const int srcB = c + 16 * ((2 * g + 1) & 3);
    const bool low = (g < 2);

    float ac0[2] = {0.f, 0.f}, ac1[2] = {0.f, 0.f};   // split by slot parity

    // ---- compute: 10 independent register-resident chains ----
    #pragma unroll
    for (int slot = 0; slot < 10; ++slot) {
        const int team = slot / 5;

        const f16x8 h10 = hrelu8(hfma8(w1gA[team], glv[team], pa0[slot]));
        const f16x8 h11 = hrelu8(hfma8(w1gB[team], glv[team], pa1[slot]));

        // layer 2: h2^T[m][c], b2 folded as C-in
        f32x4 a0 = b2lo[team], a1 = b2hi[team];
        a0 = __builtin_amdgcn_mfma_f32_16x16x32_f16(w2A[team][0][0], h10, a0, 0, 0, 0);
        a0 = __builtin_amdgcn_mfma_f32_16x16x32_f16(w2A[team][0][1], h11, a0, 0, 0, 0);
        a1 = __builtin_amdgcn_mfma_f32_16x16x32_f16(w2A[team][1][0], h10, a1, 0, 0, 0);
        a1 = __builtin_amdgcn_mfma_f32_16x16x32_f16(w2A[team][1][1], h11, a1, 0, 0, 0);

        // relu + pack; lane (c,g') holds m = 4g'+q (tile0) / 16+4g'+q (tile1)
        const int pk00 = pack2(fmaxf(a0[0], 0.f), fmaxf(a0[1], 0.f));
        const int pk01 = pack2(fmaxf(a0[2], 0.f), fmaxf(a0[3], 0.f));
        const int pk10 = pack2(fmaxf(a1[0], 0.f), fmaxf(a1[1], 0.f));
        const int pk11 = pack2(fmaxf(a1[2], 0.f), fmaxf(a1[3], 0.f));

        // redistribute -> layer-3 B-frag (verified in round 6)
        const int sA00 = __shfl(pk00, srcA, 64);
        const int sA01 = __shfl(pk01, srcA, 64);
        const int sA10 = __shfl(pk10, srcA, 64);
        const int sA11 = __shfl(pk11, srcA, 64);
        const int sB00 = __shfl(pk00, srcB, 64);
        const int sB01 = __shfl(pk01, srcB, 64);
        const int sB10 = __shfl(pk10, srcB, 64);
        const int sB11 = __shfl(pk11, srcB, 64);

        union { int u[4]; f16x8 v; } bf3;
        bf3.u[0] = low ? sA00 : sA10;
        bf3.u[1] = low ? sA01 : sA11;
        bf3.u[2] = low ? sB00 : sB10;
        bf3.u[3] = low ? sB01 : sB11;

        // layer 3: h3^T[t][c], b3 folded as C-in
        f32x4 a3 = b3v[team];
        a3 = __builtin_amdgcn_mfma_f32_16x16x32_f16(w3A[team], bf3.v, a3, 0, 0, 0);

        // final layer: lane holds h3[t = 4g+q][sample c]
        const float* __restrict__ wfb = wsf + WFP_F + 2 * (slot * 16) + 8 * g;
        const float4 wfA = *(const float4*)(wfb);
        const float4 wfB = *(const float4*)(wfb + 4);
        const float h30 = fmaxf(a3[0], 0.f);
        const float h31 = fmaxf(a3[1], 0.f);
        const float h32 = fmaxf(a3[2], 0.f);
        const float h33 = fmaxf(a3[3], 0.f);
        ac0[slot & 1] = fmaf(wfA.x, h30, ac0[slot & 1]);
        ac1[slot & 1] = fmaf(wfA.y, h30, ac1[slot & 1]);
        ac0[slot & 1] = fmaf(wfA.z, h31, ac0[slot & 1]);
        ac1[slot & 1] = fmaf(wfA.w, h31, ac1[slot & 1]);
        ac0[slot & 1] = fmaf(wfB.x, h32, ac0[slot & 1]);
        ac1[slot & 1] = fmaf(wfB.y, h32, ac1[slot & 1]);
        ac0[slot & 1] = fmaf(wfB.z, h33, ac0[slot & 1]);
        ac1[slot & 1] = fmaf(wfB.w, h33, ac1[slot & 1]);
    }

    float accO0 = ac0[0] + ac0[1];
    float accO1 = ac1[0] + ac1[1];

    // reduce over the 4 row-groups sharing column c
    accO0 += __shfl_xor(accO0, 16, 64);
    accO0 += __shfl_xor(accO0, 32, 64);
    accO1 += __shfl_xor(accO1, 16, 64);
    accO1 += __shfl_xor(accO1, 32, 64);

    if (l < 16 && sample < nB) {
        reinterpret_cast<float2*>(out)[sample] =
            make_float2(accO0 + bf[0], accO1 + bf[1]);
    }
}

extern "C" void kernel_launch(void* const* d_in, const int* in_sizes, int n_in,
                              void* d_out, int out_size, void* d_ws, size_t ws_size,
                              hipStream_t stream) {
    const float* feat = (const float*)d_in[0];
    const float* emb  = (const float*)d_in[1];
    const float* W1a  = (const float*)d_in[2];
    const float* b1a  = (const float*)d_in[3];
    const float* W2a  = (const float*)d_in[4];
    const float* b2a  = (const float*)d_in[5];
    const float* W3a  = (const float*)d_in[6];
    const float* b3a  = (const float*)d_in[7];
    const float* W1b  = (const float*)d_in[8];
    const float* b1b  = (const float*)d_in[9];
    const float* W2b  = (const float*)d_in[10];
    const float* b2b  = (const float*)d_in[11];
    const float* W3b  = (const float*)d_in[12];
    const float* b3b  = (const float*)d_in[13];
    const float* Wf   = (const float*)d_in[14];
    const float* bf   = (const float*)d_in[15];
    float* out = (float*)d_out;
    _Float16* ws16 = (_Float16*)d_ws;

    const int nB = in_sizes[0] / 12;

    precompute<<<dim3(171, 2), 64, 0, stream>>>(emb,
        W1a, b1a, W2a, b2a, W3a, b3a,
        W1b, b1b, W2b, b2b, W3b, b3b, Wf, ws16);

    const int blocks = (nB + 63) / 64;
    match_predict<<<blocks, 256, 0, stream>>>(feat, ws16, bf, out, nB);
}

// Round 8
// 49.162 us; speedup vs baseline: 4.7658x; 1.6365x over previous
//
#include <hip/hip_runtime.h>

typedef _Float16 f16x8 __attribute__((ext_vector_type(8)));
typedef _Float16 f16x4 __attribute__((ext_vector_type(4)));
typedef float    f32x4 __attribute__((ext_vector_type(4)));

// ---- global ws layout (halfword units), produced by precompute ----
#define PRE_OFF   0
#define PRE_SZ    (2 * 170 * 64)
#define W1G_OFF   (PRE_OFF + PRE_SZ)          // 21760 (128 hw)
#define W2P_OFF   (W1G_OFF + 2 * 64)          // 21888 (4096 hw)
#define W3P_OFF   (W2P_OFF + 2 * 32 * 64)     // 25984 (1024 hw)
#define H16_END   (W3P_OFF + 2 * 16 * 32)     // 27008
#define FOFF      ((H16_END + 3) & ~3)        // 27008
#define B2P_F     0
#define B3P_F     (B2P_F + 2 * 32)            // 64
#define WFP_F     (B3P_F + 2 * 16)            // 96  (+320) -> 416 floats total

// ---- LDS layout ----
// sm16: pre [340 rows][stride 72]  (bank spread: 72hw=36 words, 4ci%32 -> ~2-way)
//       then W1G(128) | W2P(4096) | W3P(1024) copied contiguously from ws
#define L_PRE   0
#define L_W1    24480
#define L_W2    (L_W1 + 128)                  // 24608
#define L_W3    (L_W2 + 4096)                 // 28704
#define L_END   (L_W3 + 1024)                 // 29728 hw
#define LF_B2   0
#define LF_B3   64
#define LF_WF   96                            // 416 floats total

__global__ void precompute(const float* __restrict__ emb,
                           const float* __restrict__ W1a, const float* __restrict__ b1a,
                           const float* __restrict__ W2a, const float* __restrict__ b2a,
                           const float* __restrict__ W3a, const float* __restrict__ b3a,
                           const float* __restrict__ W1b, const float* __restrict__ b1b,
                           const float* __restrict__ W2b, const float* __restrict__ b2b,
                           const float* __restrict__ W3b, const float* __restrict__ b3b,
                           const float* __restrict__ Wf,
                           _Float16* __restrict__ ws16)
{
    const int team = blockIdx.y;
    const float* __restrict__ W1 = team ? W1b : W1a;
    const float* __restrict__ B1 = team ? b1b : b1a;
    const float* __restrict__ W2 = team ? W2b : W2a;
    const float* __restrict__ B2 = team ? b2b : b2a;
    const float* __restrict__ W3 = team ? W3b : W3a;
    const float* __restrict__ B3 = team ? b3b : b3a;
    float* __restrict__ wsf = (float*)(ws16 + FOFF);
    const int tid = threadIdx.x;

    if (blockIdx.x < 170) {
        const int cc = blockIdx.x;
        const int k = tid;
        float v = 0.0f;
        if (k < 50) {
            v = B1[k];
            for (int d = 0; d < 50; ++d)
                v = fmaf(W1[k * 51 + d], emb[cc * 50 + d], v);
        }
        ws16[PRE_OFF + team * 170 * 64 + cc * 64 + k] = (_Float16)v;
    } else {
        for (int i = tid; i < 64; i += 64)
            ws16[W1G_OFF + team * 64 + i] = (_Float16)((i < 50) ? W1[i * 51 + 50] : 0.0f);
        for (int i = tid; i < 32 * 64; i += 64) {
            const int m = i >> 6, k = i & 63;
            ws16[W2P_OFF + team * 2048 + i] =
                (_Float16)((m < 25 && k < 50) ? W2[m * 50 + k] : 0.0f);
        }
        for (int i = tid; i < 16 * 32; i += 64) {
            const int t = i >> 5, m = i & 31;
            ws16[W3P_OFF + team * 512 + i] =
                (_Float16)((t < 10 && m < 25) ? W3[t * 25 + m] : 0.0f);
        }
        for (int i = tid; i < 32; i += 64) wsf[B2P_F + team * 32 + i] = (i < 25) ? B2[i] : 0.0f;
        for (int i = tid; i < 16; i += 64) wsf[B3P_F + team * 16 + i] = (i < 10) ? B3[i] : 0.0f;
        for (int i = tid; i < 5 * 16; i += 64) {
            const int s = i >> 4, cc2 = i & 15;
            const int o = (team * 5 + s) * 16 + cc2;
            wsf[WFP_F + 2 * o + 0] = (cc2 < 10) ? Wf[team * 50 + s * 10 + cc2] : 0.0f;
            wsf[WFP_F + 2 * o + 1] = (cc2 < 10) ? Wf[100 + team * 50 + s * 10 + cc2] : 0.0f;
        }
    }
}

__device__ __forceinline__ f16x8 hfma8(f16x8 a, f16x8 b, f16x8 c) {
    return __builtin_elementwise_fma(a, b, c);
}
__device__ __forceinline__ f16x8 hrelu8(f16x8 a) {
    const f16x8 z = {0, 0, 0, 0, 0, 0, 0, 0};
    return __builtin_elementwise_max(a, z);
}

// Block = 512 threads (8 waves), each wave owns 16 samples. All tables staged
// in LDS (61 KB; pre-table restrided to 72hw rows -> ~2-way bank aliasing on
// the ci-gather, which is free). Rounds 5-7 plateaued at ~77us because every
// slot chain waited on L2-latency scattered VMEM gathers; now they're
// ds_read_b128. Layer 3 uses two K=16 MFMAs whose B-frag (k=4g+q per lane)
// IS layer 2's C-frag (rows m=4g+q) -> the 80 bpermutes/wave are gone.
__global__ __launch_bounds__(512)
__attribute__((amdgpu_waves_per_eu(4, 8)))
void match_predict(const float* __restrict__ feat, const _Float16* __restrict__ ws16,
                   const float* __restrict__ bf, float* __restrict__ out, int nB)
{
    __shared__ __align__(16) _Float16 sm16[L_END];
    __shared__ __align__(16) float    smf[416];

    const int tid = threadIdx.x;

    // ---- stage tables: global ws -> LDS ----
    for (int i = tid; i < 340 * 8; i += 512) {           // pre rows, restride 64->72
        const int r = i >> 3, ch = i & 7;
        *(f16x8*)(sm16 + L_PRE + r * 72 + ch * 8) =
            *(const f16x8*)(ws16 + PRE_OFF + r * 64 + ch * 8);
    }
    for (int i = tid; i < (128 + 4096 + 1024) / 8; i += 512)  // w1g|w2|w3 contiguous
        *(f16x8*)(sm16 + L_W1 + i * 8) = *(const f16x8*)(ws16 + W1G_OFF + i * 8);
    for (int i = tid; i < 104; i += 512)                 // 416 floats
        *(f32x4*)(smf + i * 4) = *(const f32x4*)((const float*)(ws16 + FOFF) + i * 4);
    __syncthreads();

    const int l  = tid & 63;
    const int c  = l & 15;          // sample column
    const int g  = l >> 4;          // k-chunk / row group
    const int wv = tid >> 6;

    const int base = (blockIdx.x * 8 + wv) * 16;
    if (base >= nB) return;
    const int sample = base + c;
    const int sEff   = (sample < nB) ? sample : (nB - 1);

    const float4* f4 = reinterpret_cast<const float4*>(feat + (size_t)sEff * 12);
    const float4 v0 = f4[0], v1 = f4[1], v2 = f4[2];
    const float fr[12] = {v0.x, v0.y, v0.z, v0.w, v1.x, v1.y, v1.z, v1.w,
                          v2.x, v2.y, v2.z, v2.w};

    // ---- per-wave weight fragments from LDS ----
    f16x8 w2A[2][2][2];                            // [team][mtile][kchunk]
    f16x4 w3A0[2], w3A1[2];
    f16x8 w1gA[2], w1gB[2], glv[2];
    f32x4 b2lo[2], b2hi[2], b3v[2];
    #pragma unroll
    for (int team = 0; team < 2; ++team) {
        const _Float16* __restrict__ w2p = sm16 + L_W2 + team * 2048;
        #pragma unroll
        for (int mt = 0; mt < 2; ++mt)
            #pragma unroll
            for (int kf = 0; kf < 2; ++kf)
                w2A[team][mt][kf] =
                    *(const f16x8*)(w2p + (mt * 16 + c) * 64 + kf * 32 + g * 8);
        w3A0[team] = *(const f16x4*)(sm16 + L_W3 + team * 512 + c * 32 + 4 * g);
        w3A1[team] = *(const f16x4*)(sm16 + L_W3 + team * 512 + c * 32 + 16 + 4 * g);
        w1gA[team] = *(const f16x8*)(sm16 + L_W1 + team * 64 + g * 8);
        w1gB[team] = *(const f16x8*)(sm16 + L_W1 + team * 64 + 32 + g * 8);
        b2lo[team] = *(const f32x4*)(smf + LF_B2 + team * 32 + 4 * g);
        b2hi[team] = *(const f32x4*)(smf + LF_B2 + team * 32 + 16 + 4 * g);
        b3v[team]  = *(const f32x4*)(smf + LF_B3 + team * 16 + 4 * g);
        const _Float16 glh = (_Float16)fr[team];
        glv[team] = (f16x8){glh, glh, glh, glh, glh, glh, glh, glh};
    }

    float ac0[2] = {0.f, 0.f}, ac1[2] = {0.f, 0.f};

    #pragma unroll
    for (int slot = 0; slot < 10; ++slot) {
        const int team = slot / 5;
        const int ci = (int)fr[2 + slot];
        const _Float16* __restrict__ prow = sm16 + L_PRE + (team * 170 + ci) * 72;

        // h1^T B-frag (lane (c,g) = h1[sample c][k = chunk*32 + g*8 + i])
        const f16x8 pa0 = *(const f16x8*)(prow + g * 8);
        const f16x8 pa1 = *(const f16x8*)(prow + 32 + g * 8);
        const f16x8 h10 = hrelu8(hfma8(w1gA[team], glv[team], pa0));
        const f16x8 h11 = hrelu8(hfma8(w1gB[team], glv[team], pa1));

        // layer 2: h2^T[m][c] = W2 . h1^T, b2 as C-in
        f32x4 a0 = b2lo[team], a1 = b2hi[team];
        a0 = __builtin_amdgcn_mfma_f32_16x16x32_f16(w2A[team][0][0], h10, a0, 0, 0, 0);
        a0 = __builtin_amdgcn_mfma_f32_16x16x32_f16(w2A[team][0][1], h11, a0, 0, 0, 0);
        a1 = __builtin_amdgcn_mfma_f32_16x16x32_f16(w2A[team][1][0], h10, a1, 0, 0, 0);
        a1 = __builtin_amdgcn_mfma_f32_16x16x32_f16(w2A[team][1][1], h11, a1, 0, 0, 0);

        // relu + pack: lane (c,g) holds m = 4g+q (a0) and 16+4g+q (a1) --
        // exactly the K=16 B-frag slots k = 4g+q of the two layer-3 MFMAs.
        f16x4 b3t0, b3t1;
        b3t0.x = (_Float16)fmaxf(a0[0], 0.f);
        b3t0.y = (_Float16)fmaxf(a0[1], 0.f);
        b3t0.z = (_Float16)fmaxf(a0[2], 0.f);
        b3t0.w = (_Float16)fmaxf(a0[3], 0.f);
        b3t1.x = (_Float16)fmaxf(a1[0], 0.f);
        b3t1.y = (_Float16)fmaxf(a1[1], 0.f);
        b3t1.z = (_Float16)fmaxf(a1[2], 0.f);
        b3t1.w = (_Float16)fmaxf(a1[3], 0.f);

        // layer 3: h3^T[t][c] = W3 . h2^T over m-tiles {0..15},{16..31}
        f32x4 a3 = b3v[team];
        a3 = __builtin_amdgcn_mfma_f32_16x16x16f16(w3A0[team], b3t0, a3, 0, 0, 0);
        a3 = __builtin_amdgcn_mfma_f32_16x16x16f16(w3A1[team], b3t1, a3, 0, 0, 0);

        // final layer: lane holds h3[t = 4g+q][sample c]; wf zero-padded t>=10
        const float* __restrict__ wfb = smf + LF_WF + 2 * (slot * 16) + 8 * g;
        const f32x4 wfA = *(const f32x4*)(wfb);
        const f32x4 wfB = *(const f32x4*)(wfb + 4);
        const float h30 = fmaxf(a3[0], 0.f);
        const float h31 = fmaxf(a3[1], 0.f);
        const float h32 = fmaxf(a3[2], 0.f);
        const float h33 = fmaxf(a3[3], 0.f);
        ac0[slot & 1] = fmaf(wfA[0], h30, ac0[slot & 1]);
        ac1[slot & 1] = fmaf(wfA[1], h30, ac1[slot & 1]);
        ac0[slot & 1] = fmaf(wfA[2], h31, ac0[slot & 1]);
        ac1[slot & 1] = fmaf(wfA[3], h31, ac1[slot & 1]);
        ac0[slot & 1] = fmaf(wfB[0], h32, ac0[slot & 1]);
        ac1[slot & 1] = fmaf(wfB[1], h32, ac1[slot & 1]);
        ac0[slot & 1] = fmaf(wfB[2], h33, ac0[slot & 1]);
        ac1[slot & 1] = fmaf(wfB[3], h33, ac1[slot & 1]);
    }

    float accO0 = ac0[0] + ac0[1];
    float accO1 = ac1[0] + ac1[1];

    accO0 += __shfl_xor(accO0, 16, 64);
    accO0 += __shfl_xor(accO0, 32, 64);
    accO1 += __shfl_xor(accO1, 16, 64);
    accO1 += __shfl_xor(accO1, 32, 64);

    if (l < 16 && sample < nB) {
        reinterpret_cast<float2*>(out)[sample] =
            make_float2(accO0 + bf[0], accO1 + bf[1]);
    }
}

extern "C" void kernel_launch(void* const* d_in, const int* in_sizes, int n_in,
                              void* d_out, int out_size, void* d_ws, size_t ws_size,
                              hipStream_t stream) {
    const float* feat = (const float*)d_in[0];
    const float* emb  = (const float*)d_in[1];
    const float* W1a  = (const float*)d_in[2];
    const float* b1a  = (const float*)d_in[3];
    const float* W2a  = (const float*)d_in[4];
    const float* b2a  = (const float*)d_in[5];
    const float* W3a  = (const float*)d_in[6];
    const float* b3a  = (const float*)d_in[7];
    const float* W1b  = (const float*)d_in[8];
    const float* b1b  = (const float*)d_in[9];
    const float* W2b  = (const float*)d_in[10];
    const float* b2b  = (const float*)d_in[11];
    const float* W3b  = (const float*)d_in[12];
    const float* b3b  = (const float*)d_in[13];
    const float* Wf   = (const float*)d_in[14];
    const float* bf   = (const float*)d_in[15];
    float* out = (float*)d_out;
    _Float16* ws16 = (_Float16*)d_ws;

    const int nB = in_sizes[0] / 12;

    precompute<<<dim3(171, 2), 64, 0, stream>>>(emb,
        W1a, b1a, W2a, b2a, W3a, b3a,
        W1b, b1b, W2b, b2b, W3b, b3b, Wf, ws16);

    const int blocks = (nB + 127) / 128;
    match_predict<<<blocks, 512, 0, stream>>>(feat, ws16, bf, out, nB);
}

// Round 10
// 39.654 us; speedup vs baseline: 5.9084x; 1.2398x over previous
//
#include <hip/hip_runtime.h>

typedef _Float16 f16x8 __attribute__((ext_vector_type(8)));
typedef _Float16 f16x4 __attribute__((ext_vector_type(4)));
typedef _Float16 f16x2 __attribute__((ext_vector_type(2)));
typedef float    f32x4 __attribute__((ext_vector_type(4)));

// ---- global ws layout (halfword units), produced by precompute ----
#define PRE_OFF   0
#define PRE_SZ    (2 * 170 * 64)
#define W1G_OFF   (PRE_OFF + PRE_SZ)          // 21760 (128 hw)
#define W2P_OFF   (W1G_OFF + 2 * 64)          // 21888 (4096 hw, [64 rows][64])
#define W3P_OFF   (W2P_OFF + 2 * 32 * 64)     // 25984 (1024 hw, [32 rows][32])
#define H16_END   (W3P_OFF + 2 * 16 * 32)     // 27008
#define FOFF      ((H16_END + 3) & ~3)        // 27008
#define B2P_F     0
#define B3P_F     (B2P_F + 2 * 32)            // 64
#define WFP_F     (B3P_F + 2 * 16)            // 96  (+320) -> 416 floats

// ---- LDS layout (halfword units) ----
// pre [340][72]  : ci-gather rows; stride 72 hw -> start bank 4*ci%32, ~2-way
// w1g [2][64]    : wave-uniform per g -> broadcast reads
// w2  [64][72]   : stride 72 hw -> start bank 4c%32, 2-way (was 64 hw: 16-way!)
// w3  [32][40]   : stride 40 hw -> 2-way (was 32 hw: 8-way)
#define L_PRE   0
#define L_W1    24480
#define L_W2    (L_W1 + 128)                  // 24608
#define L_W3    (L_W2 + 64 * 72)              // 29216
#define L_END   (L_W3 + 32 * 40)              // 30496 hw = 60992 B

__global__ void precompute(const float* __restrict__ emb,
                           const float* __restrict__ W1a, const float* __restrict__ b1a,
                           const float* __restrict__ W2a, const float* __restrict__ b2a,
                           const float* __restrict__ W3a, const float* __restrict__ b3a,
                           const float* __restrict__ W1b, const float* __restrict__ b1b,
                           const float* __restrict__ W2b, const float* __restrict__ b2b,
                           const float* __restrict__ W3b, const float* __restrict__ b3b,
                           const float* __restrict__ Wf,
                           _Float16* __restrict__ ws16)
{
    const int team = blockIdx.y;
    const float* __restrict__ W1 = team ? W1b : W1a;
    const float* __restrict__ B1 = team ? b1b : b1a;
    const float* __restrict__ W2 = team ? W2b : W2a;
    const float* __restrict__ B2 = team ? b2b : b2a;
    const float* __restrict__ W3 = team ? W3b : W3a;
    const float* __restrict__ B3 = team ? b3b : b3a;
    float* __restrict__ wsf = (float*)(ws16 + FOFF);
    const int tid = threadIdx.x;

    if (blockIdx.x < 170) {
        const int cc = blockIdx.x;
        const int k = tid;
        float v = 0.0f;
        if (k < 50) {
            v = B1[k];
            for (int d = 0; d < 50; ++d)
                v = fmaf(W1[k * 51 + d], emb[cc * 50 + d], v);
        }
        ws16[PRE_OFF + team * 170 * 64 + cc * 64 + k] = (_Float16)v;
    } else {
        for (int i = tid; i < 64; i += 64)
            ws16[W1G_OFF + team * 64 + i] = (_Float16)((i < 50) ? W1[i * 51 + 50] : 0.0f);
        for (int i = tid; i < 32 * 64; i += 64) {
            const int m = i >> 6, k = i & 63;
            ws16[W2P_OFF + team * 2048 + i] =
                (_Float16)((m < 25 && k < 50) ? W2[m * 50 + k] : 0.0f);
        }
        for (int i = tid; i < 16 * 32; i += 64) {
            const int t = i >> 5, m = i & 31;
            ws16[W3P_OFF + team * 512 + i] =
                (_Float16)((t < 10 && m < 25) ? W3[t * 25 + m] : 0.0f);
        }
        for (int i = tid; i < 32; i += 64) wsf[B2P_F + team * 32 + i] = (i < 25) ? B2[i] : 0.0f;
        for (int i = tid; i < 16; i += 64) wsf[B3P_F + team * 16 + i] = (i < 10) ? B3[i] : 0.0f;
        for (int i = tid; i < 5 * 16; i += 64) {
            const int s = i >> 4, cc2 = i & 15;
            const int o = (team * 5 + s) * 16 + cc2;
            wsf[WFP_F + 2 * o + 0] = (cc2 < 10) ? Wf[team * 50 + s * 10 + cc2] : 0.0f;
            wsf[WFP_F + 2 * o + 1] = (cc2 < 10) ? Wf[100 + team * 50 + s * 10 + cc2] : 0.0f;
        }
    }
}

__device__ __forceinline__ f16x8 hfma8(f16x8 a, f16x8 b, f16x8 c) {
    return __builtin_elementwise_fma(a, b, c);
}
__device__ __forceinline__ f16x8 hrelu8(f16x8 a) {
    const f16x8 z = {0, 0, 0, 0, 0, 0, 0, 0};
    return __builtin_elementwise_max(a, z);
}
__device__ __forceinline__ f16x2 pkrtz(float a, float b) {
    return __builtin_bit_cast(f16x2, __builtin_amdgcn_cvt_pkrtz(a, b));
}

// 512 threads / 8 waves; wave owns 16 samples, operand-swapped MFMAs.
// Round-9 deltas vs round 8 (40us, 30MB spill-writes, 6M bank-conflict cy):
//  * waves_per_eu(4,4): pin allocator at the 128-VGPR / 4-waves-per-EU point
//    (4,8) made it target 8 waves -> 64 VGPRs -> spilled weight frags.
//  * team-sequential outer loop halves the live fragment set (~40 VGPRs).
//  * W2 LDS stride 64->72 hw, W3 32->40 hw: kills the 16-way/8-way read
//    conflicts (start bank now 4c%32 / distinct -> ~2-way = free).
__global__ __launch_bounds__(512)
__attribute__((amdgpu_waves_per_eu(4, 4)))
void match_predict(const float* __restrict__ feat, const _Float16* __restrict__ ws16,
                   const float* __restrict__ bf, float* __restrict__ out, int nB)
{
    __shared__ __align__(16) _Float16 sm16[L_END];
    __shared__ __align__(16) float    smf[416];

    const int tid = threadIdx.x;
    const int l  = tid & 63;
    const int c  = l & 15;          // sample column
    const int g  = l >> 4;          // k-chunk / row group
    const int wv = tid >> 6;

    const int base = (blockIdx.x * 8 + wv) * 16;
    const int sample = base + c;
    const int sEff   = (sample < nB) ? sample : (nB - 1);

    // issue the feature load early; it overlaps the LDS staging below
    const float4* f4 = reinterpret_cast<const float4*>(feat + (size_t)sEff * 12);
    const float4 v0 = f4[0], v1 = f4[1], v2 = f4[2];

    // ---- stage tables: global ws -> LDS (restriding rows for bank spread) ----
    for (int i = tid; i < 340 * 8; i += 512) {            // pre: 64 -> 72 stride
        const int r = i >> 3, ch = i & 7;
        *(f16x8*)(sm16 + L_PRE + r * 72 + ch * 8) =
            *(const f16x8*)(ws16 + PRE_OFF + r * 64 + ch * 8);
    }
    for (int i = tid; i < 16; i += 512)                   // w1g contiguous
        *(f16x8*)(sm16 + L_W1 + i * 8) = *(const f16x8*)(ws16 + W1G_OFF + i * 8);
    for (int i = tid; i < 64 * 8; i += 512) {             // w2: 64 -> 72 stride
        const int r = i >> 3, ch = i & 7;
        *(f16x8*)(sm16 + L_W2 + r * 72 + ch * 8) =
            *(const f16x8*)(ws16 + W2P_OFF + r * 64 + ch * 8);
    }
    for (int i = tid; i < 32 * 4; i += 512) {             // w3: 32 -> 40 stride
        const int r = i >> 2, ch = i & 3;
        *(f16x8*)(sm16 + L_W3 + r * 40 + ch * 8) =
            *(const f16x8*)(ws16 + W3P_OFF + r * 32 + ch * 8);
    }
    for (int i = tid; i < 104; i += 512)                  // 416 floats
        *(f32x4*)(smf + i * 4) = *(const f32x4*)((const float*)(ws16 + FOFF) + i * 4);
    __syncthreads();

    if (base >= nB) return;

    const float fr[12] = {v0.x, v0.y, v0.z, v0.w, v1.x, v1.y, v1.z, v1.w,
                          v2.x, v2.y, v2.z, v2.w};

    float ac0[2] = {0.f, 0.f}, ac1[2] = {0.f, 0.f};

    #pragma unroll
    for (int team = 0; team < 2; ++team) {
        // ---- this team's fragments from LDS (live set ~40 VGPRs) ----
        f16x8 w2A[2][2];                       // [mtile][kchunk]
        #pragma unroll
        for (int mt = 0; mt < 2; ++mt)
            #pragma unroll
            for (int kf = 0; kf < 2; ++kf)
                w2A[mt][kf] = *(const f16x8*)(sm16 + L_W2 + (team * 32 + mt * 16 + c) * 72
                                              + kf * 32 + g * 8);
        const f16x4 w3A0 = *(const f16x4*)(sm16 + L_W3 + (team * 16 + c) * 40 + 4 * g);
        const f16x4 w3A1 = *(const f16x4*)(sm16 + L_W3 + (team * 16 + c) * 40 + 16 + 4 * g);
        const f16x8 w1gA = *(const f16x8*)(sm16 + L_W1 + team * 64 + g * 8);
        const f16x8 w1gB = *(const f16x8*)(sm16 + L_W1 + team * 64 + 32 + g * 8);
        const f32x4 b2lo = *(const f32x4*)(smf + B2P_F + team * 32 + 4 * g);
        const f32x4 b2hi = *(const f32x4*)(smf + B2P_F + team * 32 + 16 + 4 * g);
        const f32x4 b3v  = *(const f32x4*)(smf + B3P_F + team * 16 + 4 * g);
        const _Float16 glh = (_Float16)fr[team];
        const f16x8 glv = {glh, glh, glh, glh, glh, glh, glh, glh};

        #pragma unroll
        for (int s5 = 0; s5 < 5; ++s5) {
            const int slot = team * 5 + s5;
            const int ci = (int)fr[2 + slot];
            const _Float16* __restrict__ prow = sm16 + L_PRE + (team * 170 + ci) * 72;

            // h1^T B-frag (lane (c,g) = h1[sample c][k = chunk*32 + g*8 + i])
            const f16x8 pa0 = *(const f16x8*)(prow + g * 8);
            const f16x8 pa1 = *(const f16x8*)(prow + 32 + g * 8);
            const f16x8 h10 = hrelu8(hfma8(w1gA, glv, pa0));
            const f16x8 h11 = hrelu8(hfma8(w1gB, glv, pa1));

            // layer 2: h2^T[m][c] = W2 . h1^T, b2 as C-in
            f32x4 a0 = b2lo, a1 = b2hi;
            a0 = __builtin_amdgcn_mfma_f32_16x16x32_f16(w2A[0][0], h10, a0, 0, 0, 0);
            a0 = __builtin_amdgcn_mfma_f32_16x16x32_f16(w2A[0][1], h11, a0, 0, 0, 0);
            a1 = __builtin_amdgcn_mfma_f32_16x16x32_f16(w2A[1][0], h10, a1, 0, 0, 0);
            a1 = __builtin_amdgcn_mfma_f32_16x16x32_f16(w2A[1][1], h11, a1, 0, 0, 0);

            // relu + pack (RTZ): lane (c,g) holds m=4g+q / 16+4g+q -- exactly
            // the K=16 B-frag slots k=4g+q of the two layer-3 MFMAs.
            const f16x2 p00 = pkrtz(fmaxf(a0[0], 0.f), fmaxf(a0[1], 0.f));
            const f16x2 p01 = pkrtz(fmaxf(a0[2], 0.f), fmaxf(a0[3], 0.f));
            const f16x2 p10 = pkrtz(fmaxf(a1[0], 0.f), fmaxf(a1[1], 0.f));
            const f16x2 p11 = pkrtz(fmaxf(a1[2], 0.f), fmaxf(a1[3], 0.f));
            const f16x4 b3t0 = {p00.x, p00.y, p01.x, p01.y};
            const f16x4 b3t1 = {p10.x, p10.y, p11.x, p11.y};

            // layer 3: h3^T[t][c] = W3 . h2^T over m-tiles {0..15},{16..31}
            f32x4 a3 = b3v;
            a3 = __builtin_amdgcn_mfma_f32_16x16x16f16(w3A0, b3t0, a3, 0, 0, 0);
            a3 = __builtin_amdgcn_mfma_f32_16x16x16f16(w3A1, b3t1, a3, 0, 0, 0);

            // final layer: lane holds h3[t = 4g+q][sample c]; wf zero-padded t>=10
            const float* __restrict__ wfb = smf + WFP_F + 2 * (slot * 16) + 8 * g;
            const f32x4 wfA = *(const f32x4*)(wfb);
            const f32x4 wfB = *(const f32x4*)(wfb + 4);
            const float h30 = fmaxf(a3[0], 0.f);
            const float h31 = fmaxf(a3[1], 0.f);
            const float h32 = fmaxf(a3[2], 0.f);
            const float h33 = fmaxf(a3[3], 0.f);
            ac0[s5 & 1] = fmaf(wfA[0], h30, ac0[s5 & 1]);
            ac1[s5 & 1] = fmaf(wfA[1], h30, ac1[s5 & 1]);
            ac0[s5 & 1] = fmaf(wfA[2], h31, ac0[s5 & 1]);
            ac1[s5 & 1] = fmaf(wfA[3], h31, ac1[s5 & 1]);
            ac0[s5 & 1] = fmaf(wfB[0], h32, ac0[s5 & 1]);
            ac1[s5 & 1] = fmaf(wfB[1], h32, ac1[s5 & 1]);
            ac0[s5 & 1] = fmaf(wfB[2], h33, ac0[s5 & 1]);
            ac1[s5 & 1] = fmaf(wfB[3], h33, ac1[s5 & 1]);
        }
    }

    float accO0 = ac0[0] + ac0[1];
    float accO1 = ac1[0] + ac1[1];

    accO0 += __shfl_xor(accO0, 16, 64);
    accO0 += __shfl_xor(accO0, 32, 64);
    accO1 += __shfl_xor(accO1, 16, 64);
    accO1 += __shfl_xor(accO1, 32, 64);

    if (l < 16 && sample < nB) {
        reinterpret_cast<float2*>(out)[sample] =
            make_float2(accO0 + bf[0], accO1 + bf[1]);
    }
}

extern "C" void kernel_launch(void* const* d_in, const int* in_sizes, int n_in,
                              void* d_out, int out_size, void* d_ws, size_t ws_size,
                              hipStream_t stream) {
    const float* feat = (const float*)d_in[0];
    const float* emb  = (const float*)d_in[1];
    const float* W1a  = (const float*)d_in[2];
    const float* b1a  = (const float*)d_in[3];
    const float* W2a  = (const float*)d_in[4];
    const float* b2a  = (const float*)d_in[5];
    const float* W3a  = (const float*)d_in[6];
    const float* b3a  = (const float*)d_in[7];
    const float* W1b  = (const float*)d_in[8];
    const float* b1b  = (const float*)d_in[9];
    const float* W2b  = (const float*)d_in[10];
    const float* b2b  = (const float*)d_in[11];
    const float* W3b  = (const float*)d_in[12];
    const float* b3b  = (const float*)d_in[13];
    const float* Wf   = (const float*)d_in[14];
    const float* bf   = (const float*)d_in[15];
    float* out = (float*)d_out;
    _Float16* ws16 = (_Float16*)d_ws;

    const int nB = in_sizes[0] / 12;

    precompute<<<dim3(171, 2), 64, 0, stream>>>(emb,
        W1a, b1a, W2a, b2a, W3a, b3a,
        W1b, b1b, W2b, b2b, W3b, b3b, Wf, ws16);

    const int blocks = (nB + 127) / 128;
    match_predict<<<blocks, 512, 0, stream>>>(feat, ws16, bf, out, nB);
}

// Round 11
// 39.504 us; speedup vs baseline: 5.9309x; 1.0038x over previous
//
#include <hip/hip_runtime.h>

typedef _Float16 f16x8 __attribute__((ext_vector_type(8)));
typedef _Float16 f16x4 __attribute__((ext_vector_type(4)));
typedef _Float16 f16x2 __attribute__((ext_vector_type(2)));
typedef float    f32x4 __attribute__((ext_vector_type(4)));

// ---- global ws layout (halfword units), produced by precompute ----
#define PRE_OFF   0
#define PRE_SZ    (2 * 170 * 64)
#define W1G_OFF   (PRE_OFF + PRE_SZ)          // 21760 (128 hw)
#define W2P_OFF   (W1G_OFF + 2 * 64)          // 21888 (4096 hw, [64 rows][64])
#define W3P_OFF   (W2P_OFF + 2 * 32 * 64)     // 25984 (1024 hw, [32 rows][32])
#define WFR_OFF   (W3P_OFF + 2 * 16 * 32)     // 27008 ([2][5][2 rows][16 k] = 320 hw)
#define H16_END   (WFR_OFF + 320)             // 27328
#define FOFF      H16_END                     // 27328 (x2B = 54656, 16B-aligned)
#define B2P_F     0
#define B3P_F     (B2P_F + 2 * 32)            // 64  (+32) -> 96 floats

// ---- LDS layout (halfword units; ALL strides mult. of 8 hw for 16B align) ----
// pre [340][72] : gather rows, bank (4(ci+g))%32 -> ~2-way, free
// w1g [2][64]   : broadcast reads
// w2  [64][72]  : bank (4c+..)%32 -> ~2-way
// w3  [32][40]  : ~2-way
// wfr [10][40]  : 2 real rows/slot at +0,+16; reads 8 distinct addrs -> 2-way
#define L_PRE   0
#define L_W1    24480
#define L_W2    (L_W1 + 128)                  // 24608
#define L_W3    (L_W2 + 64 * 72)              // 29216
#define L_WFR   (L_W3 + 32 * 40)              // 30496
#define L_END   (L_WFR + 10 * 40)             // 30896 hw = 61792 B

__global__ void precompute(const float* __restrict__ emb,
                           const float* __restrict__ W1a, const float* __restrict__ b1a,
                           const float* __restrict__ W2a, const float* __restrict__ b2a,
                           const float* __restrict__ W3a, const float* __restrict__ b3a,
                           const float* __restrict__ W1b, const float* __restrict__ b1b,
                           const float* __restrict__ W2b, const float* __restrict__ b2b,
                           const float* __restrict__ W3b, const float* __restrict__ b3b,
                           const float* __restrict__ Wf,
                           _Float16* __restrict__ ws16)
{
    const int team = blockIdx.y;
    const float* __restrict__ W1 = team ? W1b : W1a;
    const float* __restrict__ B1 = team ? b1b : b1a;
    const float* __restrict__ W2 = team ? W2b : W2a;
    const float* __restrict__ B2 = team ? b2b : b2a;
    const float* __restrict__ W3 = team ? W3b : W3a;
    const float* __restrict__ B3 = team ? b3b : b3a;
    float* __restrict__ wsf = (float*)(ws16 + FOFF);
    const int tid = threadIdx.x;

    if (blockIdx.x < 170) {
        const int cc = blockIdx.x;
        const int k = tid;
        float v = 0.0f;
        if (k < 50) {
            v = B1[k];
            for (int d = 0; d < 50; ++d)
                v = fmaf(W1[k * 51 + d], emb[cc * 50 + d], v);
        }
        ws16[PRE_OFF + team * 170 * 64 + cc * 64 + k] = (_Float16)v;
    } else {
        for (int i = tid; i < 64; i += 64)
            ws16[W1G_OFF + team * 64 + i] = (_Float16)((i < 50) ? W1[i * 51 + 50] : 0.0f);
        for (int i = tid; i < 32 * 64; i += 64) {
            const int m = i >> 6, k = i & 63;
            ws16[W2P_OFF + team * 2048 + i] =
                (_Float16)((m < 25 && k < 50) ? W2[m * 50 + k] : 0.0f);
        }
        for (int i = tid; i < 16 * 32; i += 64) {
            const int t = i >> 5, m = i & 31;
            ws16[W3P_OFF + team * 512 + i] =
                (_Float16)((t < 10 && m < 25) ? W3[t * 25 + m] : 0.0f);
        }
        // wfr: [team][slot s][row r=out-channel (2)][k=t (16)]
        for (int i = tid; i < 5 * 2 * 16; i += 64) {
            const int s = i >> 5, r = (i >> 4) & 1, k = i & 15;
            ws16[WFR_OFF + team * 160 + i] =
                (_Float16)((k < 10) ? Wf[r * 100 + team * 50 + s * 10 + k] : 0.0f);
        }
        for (int i = tid; i < 32; i += 64) wsf[B2P_F + team * 32 + i] = (i < 25) ? B2[i] : 0.0f;
        for (int i = tid; i < 16; i += 64) wsf[B3P_F + team * 16 + i] = (i < 10) ? B3[i] : 0.0f;
    }
}

__device__ __forceinline__ f16x8 hfma8(f16x8 a, f16x8 b, f16x8 c) {
    return __builtin_elementwise_fma(a, b, c);
}
__device__ __forceinline__ f16x8 hrelu8(f16x8 a) {
    const f16x8 z = {0, 0, 0, 0, 0, 0, 0, 0};
    return __builtin_elementwise_max(a, z);
}
__device__ __forceinline__ f16x2 pkrtz(float a, float b) {
    return __builtin_bit_cast(f16x2, __builtin_amdgcn_cvt_pkrtz(a, b));
}

// 512 threads / 8 waves; wave owns 16 samples, operand-swapped MFMAs.
// Round-11 deltas vs round 10 (~36us match_predict):
//  * final layer is a 3rd MFMA/slot: relu(h3) C-frag (t=4g+q, col c) IS the
//    16x16x16 B-frag; A = per-slot Wf rows; C accumulates across all 10 slots.
//    Deletes 20 ds_read_b128 + 120 fma VALU + 4 shfl per wave; out lands in
//    lanes g=0 as aout[0..1]. MFMA pipe was ~5% busy -> free.
//  * register double-buffer on the pre-row gathers (issue slot s+1's 2
//    ds_read_b128 before computing slot s) hides the ~120cy LDS latency that
//    the serial chain ate 10x per wave.
__global__ __launch_bounds__(512)
__attribute__((amdgpu_waves_per_eu(4, 4)))
void match_predict(const float* __restrict__ feat, const _Float16* __restrict__ ws16,
                   const float* __restrict__ bf, float* __restrict__ out, int nB)
{
    __shared__ __align__(16) _Float16 sm16[L_END];
    __shared__ __align__(16) float    smf[96];

    const int tid = threadIdx.x;
    const int l  = tid & 63;
    const int c  = l & 15;          // sample column
    const int g  = l >> 4;          // k-chunk / row group
    const int wv = tid >> 6;

    const int base = (blockIdx.x * 8 + wv) * 16;
    const int sample = base + c;
    const int sEff   = (sample < nB) ? sample : (nB - 1);

    // feature load issues before the staging barrier
    const float4* f4 = reinterpret_cast<const float4*>(feat + (size_t)sEff * 12);
    const float4 v0 = f4[0], v1 = f4[1], v2 = f4[2];

    // ---- stage tables: global ws -> LDS (restride rows for bank spread) ----
    for (int i = tid; i < 340 * 8; i += 512) {            // pre: 64 -> 72 stride
        const int r = i >> 3, ch = i & 7;
        *(f16x8*)(sm16 + L_PRE + r * 72 + ch * 8) =
            *(const f16x8*)(ws16 + PRE_OFF + r * 64 + ch * 8);
    }
    for (int i = tid; i < 16; i += 512)                   // w1g contiguous
        *(f16x8*)(sm16 + L_W1 + i * 8) = *(const f16x8*)(ws16 + W1G_OFF + i * 8);
    for (int i = tid; i < 64 * 8; i += 512) {             // w2: 64 -> 72 stride
        const int r = i >> 3, ch = i & 7;
        *(f16x8*)(sm16 + L_W2 + r * 72 + ch * 8) =
            *(const f16x8*)(ws16 + W2P_OFF + r * 64 + ch * 8);
    }
    for (int i = tid; i < 32 * 4; i += 512) {             // w3: 32 -> 40 stride
        const int r = i >> 2, ch = i & 3;
        *(f16x8*)(sm16 + L_W3 + r * 40 + ch * 8) =
            *(const f16x8*)(ws16 + W3P_OFF + r * 32 + ch * 8);
    }
    for (int i = tid; i < 40; i += 512) {                 // wfr: 32 -> 40 stride
        const int ts = i >> 2, ch = i & 3;
        *(f16x8*)(sm16 + L_WFR + ts * 40 + ch * 8) =
            *(const f16x8*)(ws16 + WFR_OFF + ts * 32 + ch * 8);
    }
    for (int i = tid; i < 24; i += 512)                   // 96 floats
        *(f32x4*)(smf + i * 4) = *(const f32x4*)((const float*)(ws16 + FOFF) + i * 4);
    __syncthreads();

    if (base >= nB) return;

    const float fr[12] = {v0.x, v0.y, v0.z, v0.w, v1.x, v1.y, v1.z, v1.w,
                          v2.x, v2.y, v2.z, v2.w};

    f32x4 aout = {0.f, 0.f, 0.f, 0.f};        // final-layer C, carried all 10 slots

    // prime the pre-row pipeline with slot 0
    f16x8 pc0, pc1;
    {
        const int ci0 = (int)fr[2];
        const _Float16* p = sm16 + L_PRE + ci0 * 72;
        pc0 = *(const f16x8*)(p + g * 8);
        pc1 = *(const f16x8*)(p + 32 + g * 8);
    }

    #pragma unroll
    for (int team = 0; team < 2; ++team) {
        // ---- this team's fragments from LDS ----
        f16x8 w2A[2][2];                       // [mtile][kchunk]
        #pragma unroll
        for (int mt = 0; mt < 2; ++mt)
            #pragma unroll
            for (int kf = 0; kf < 2; ++kf)
                w2A[mt][kf] = *(const f16x8*)(sm16 + L_W2 + (team * 32 + mt * 16 + c) * 72
                                              + kf * 32 + g * 8);
        const f16x4 w3A0 = *(const f16x4*)(sm16 + L_W3 + (team * 16 + c) * 40 + 4 * g);
        const f16x4 w3A1 = *(const f16x4*)(sm16 + L_W3 + (team * 16 + c) * 40 + 16 + 4 * g);
        const f16x8 w1gA = *(const f16x8*)(sm16 + L_W1 + team * 64 + g * 8);
        const f16x8 w1gB = *(const f16x8*)(sm16 + L_W1 + team * 64 + 32 + g * 8);
        f16x4 wfrA[5];
        #pragma unroll
        for (int s = 0; s < 5; ++s)            // 2 real rows; lanes c>=2 duplicate c&1
            wfrA[s] = *(const f16x4*)(sm16 + L_WFR + (team * 5 + s) * 40
                                      + (c & 1) * 16 + 4 * g);
        const f32x4 b2lo = *(const f32x4*)(smf + B2P_F + team * 32 + 4 * g);
        const f32x4 b2hi = *(const f32x4*)(smf + B2P_F + team * 32 + 16 + 4 * g);
        const f32x4 b3v  = *(const f32x4*)(smf + B3P_F + team * 16 + 4 * g);
        const _Float16 glh = (_Float16)fr[team];
        const f16x8 glv = {glh, glh, glh, glh, glh, glh, glh, glh};

        #pragma unroll
        for (int s5 = 0; s5 < 5; ++s5) {
            const int slot = team * 5 + s5;

            // issue next slot's pre-row reads before this slot's compute
            f16x8 pn0 = pc0, pn1 = pc1;
            if (slot < 9) {
                const int cin = (int)fr[3 + slot];
                const int tn = (slot + 1) / 5;              // literal after unroll
                const _Float16* pn = sm16 + L_PRE + (tn * 170 + cin) * 72;
                pn0 = *(const f16x8*)(pn + g * 8);
                pn1 = *(const f16x8*)(pn + 32 + g * 8);
            }

            // h1^T B-frag (lane (c,g) = h1[sample c][k = chunk*32 + g*8 + i])
            const f16x8 h10 = hrelu8(hfma8(w1gA, glv, pc0));
            const f16x8 h11 = hrelu8(hfma8(w1gB, glv, pc1));

            // layer 2: h2^T[m][c] = W2 . h1^T, b2 as C-in
            f32x4 a0 = b2lo, a1 = b2hi;
            a0 = __builtin_amdgcn_mfma_f32_16x16x32_f16(w2A[0][0], h10, a0, 0, 0, 0);
            a0 = __builtin_amdgcn_mfma_f32_16x16x32_f16(w2A[0][1], h11, a0, 0, 0, 0);
            a1 = __builtin_amdgcn_mfma_f32_16x16x32_f16(w2A[1][0], h10, a1, 0, 0, 0);
            a1 = __builtin_amdgcn_mfma_f32_16x16x32_f16(w2A[1][1], h11, a1, 0, 0, 0);

            // relu + pack: lane (c,g) holds m=4g+q / 16+4g+q = K=16 B-frag slots
            const f16x2 p00 = pkrtz(fmaxf(a0[0], 0.f), fmaxf(a0[1], 0.f));
            const f16x2 p01 = pkrtz(fmaxf(a0[2], 0.f), fmaxf(a0[3], 0.f));
            const f16x2 p10 = pkrtz(fmaxf(a1[0], 0.f), fmaxf(a1[1], 0.f));
            const f16x2 p11 = pkrtz(fmaxf(a1[2], 0.f), fmaxf(a1[3], 0.f));
            const f16x4 b3t0 = {p00.x, p00.y, p01.x, p01.y};
            const f16x4 b3t1 = {p10.x, p10.y, p11.x, p11.y};

            // layer 3: h3^T[t][c] = W3 . h2^T, b3 as C-in
            f32x4 a3 = b3v;
            a3 = __builtin_amdgcn_mfma_f32_16x16x16f16(w3A0, b3t0, a3, 0, 0, 0);
            a3 = __builtin_amdgcn_mfma_f32_16x16x16f16(w3A1, b3t1, a3, 0, 0, 0);

            // final layer: B-frag = relu(h3) (k=4g+q = t), A = Wf rows,
            // C accumulates across slots. No per-slot VALU epilogue.
            const f16x2 q0 = pkrtz(fmaxf(a3[0], 0.f), fmaxf(a3[1], 0.f));
            const f16x2 q1 = pkrtz(fmaxf(a3[2], 0.f), fmaxf(a3[3], 0.f));
            const f16x4 h3f = {q0.x, q0.y, q1.x, q1.y};
            aout = __builtin_amdgcn_mfma_f32_16x16x16f16(wfrA[s5], h3f, aout, 0, 0, 0);

            pc0 = pn0; pc1 = pn1;
        }
    }

    // aout C-frag: lane (c,g) holds C[row 4g+q][col c]; rows 0,1 (g=0,q=0/1)
    // are out0/out1 for sample c.
    if (g == 0 && sample < nB) {
        reinterpret_cast<float2*>(out)[sample] =
            make_float2(aout[0] + bf[0], aout[1] + bf[1]);
    }
}

extern "C" void kernel_launch(void* const* d_in, const int* in_sizes, int n_in,
                              void* d_out, int out_size, void* d_ws, size_t ws_size,
                              hipStream_t stream) {
    const float* feat = (const float*)d_in[0];
    const float* emb  = (const float*)d_in[1];
    const float* W1a  = (const float*)d_in[2];
    const float* b1a  = (const float*)d_in[3];
    const float* W2a  = (const float*)d_in[4];
    const float* b2a  = (const float*)d_in[5];
    const float* W3a  = (const float*)d_in[6];
    const float* b3a  = (const float*)d_in[7];
    const float* W1b  = (const float*)d_in[8];
    const float* b1b  = (const float*)d_in[9];
    const float* W2b  = (const float*)d_in[10];
    const float* b2b  = (const float*)d_in[11];
    const float* W3b  = (const float*)d_in[12];
    const float* b3b  = (const float*)d_in[13];
    const float* Wf   = (const float*)d_in[14];
    const float* bf   = (const float*)d_in[15];
    float* out = (float*)d_out;
    _Float16* ws16 = (_Float16*)d_ws;

    const int nB = in_sizes[0] / 12;

    precompute<<<dim3(171, 2), 64, 0, stream>>>(emb,
        W1a, b1a, W2a, b2a, W3a, b3a,
        W1b, b1b, W2b, b2b, W3b, b3b, Wf, ws16);

    const int blocks = (nB + 127) / 128;
    match_predict<<<blocks, 512, 0, stream>>>(feat, ws16, bf, out, nB);
}

// Round 12
// 36.274 us; speedup vs baseline: 6.4589x; 1.0890x over previous
//
#include <hip/hip_runtime.h>

typedef _Float16 f16x8 __attribute__((ext_vector_type(8)));
typedef _Float16 f16x4 __attribute__((ext_vector_type(4)));
typedef _Float16 f16x2 __attribute__((ext_vector_type(2)));
typedef float    f32x4 __attribute__((ext_vector_type(4)));

// ---- global ws layout (halfword units), produced by precompute ----
#define PRE_OFF   0
#define PRE_SZ    (2 * 170 * 64)
#define W1G_OFF   (PRE_OFF + PRE_SZ)          // 21760 (128 hw)
#define W2P_OFF   (W1G_OFF + 2 * 64)          // 21888 (4096 hw, [64 rows][64])
#define W3P_OFF   (W2P_OFF + 2 * 32 * 64)     // 25984 (1024 hw, [32 rows][32])
#define WFR_OFF   (W3P_OFF + 2 * 16 * 32)     // 27008 ([2][5][2 rows][16 k] = 320 hw)
#define H16_END   (WFR_OFF + 320)             // 27328
#define FOFF      H16_END                     // 27328 (x2B = 54656, 16B-aligned)
#define B2P_F     0
#define B3P_F     (B2P_F + 2 * 32)            // 64  (+32) -> 96 floats

// ---- LDS layout (halfword units; strides mult. of 8 hw for 16B alignment) ----
#define L_PRE   0
#define L_W1    24480
#define L_W2    (L_W1 + 128)                  // 24608
#define L_W3    (L_W2 + 64 * 72)              // 29216
#define L_WFR   (L_W3 + 32 * 40)              // 30496
#define L_END   (L_WFR + 10 * 40)             // 30896 hw = 61792 B

__global__ void precompute(const float* __restrict__ emb,
                           const float* __restrict__ W1a, const float* __restrict__ b1a,
                           const float* __restrict__ W2a, const float* __restrict__ b2a,
                           const float* __restrict__ W3a, const float* __restrict__ b3a,
                           const float* __restrict__ W1b, const float* __restrict__ b1b,
                           const float* __restrict__ W2b, const float* __restrict__ b2b,
                           const float* __restrict__ W3b, const float* __restrict__ b3b,
                           const float* __restrict__ Wf,
                           _Float16* __restrict__ ws16)
{
    const int team = blockIdx.y;
    const float* __restrict__ W1 = team ? W1b : W1a;
    const float* __restrict__ B1 = team ? b1b : b1a;
    const float* __restrict__ W2 = team ? W2b : W2a;
    const float* __restrict__ B2 = team ? b2b : b2a;
    const float* __restrict__ W3 = team ? W3b : W3a;
    const float* __restrict__ B3 = team ? b3b : b3a;
    float* __restrict__ wsf = (float*)(ws16 + FOFF);
    const int tid = threadIdx.x;

    if (blockIdx.x < 170) {
        const int cc = blockIdx.x;
        const int k = tid;
        float v = 0.0f;
        if (k < 50) {
            v = B1[k];
            for (int d = 0; d < 50; ++d)
                v = fmaf(W1[k * 51 + d], emb[cc * 50 + d], v);
        }
        ws16[PRE_OFF + team * 170 * 64 + cc * 64 + k] = (_Float16)v;
    } else {
        for (int i = tid; i < 64; i += 64)
            ws16[W1G_OFF + team * 64 + i] = (_Float16)((i < 50) ? W1[i * 51 + 50] : 0.0f);
        for (int i = tid; i < 32 * 64; i += 64) {
            const int m = i >> 6, k = i & 63;
            ws16[W2P_OFF + team * 2048 + i] =
                (_Float16)((m < 25 && k < 50) ? W2[m * 50 + k] : 0.0f);
        }
        for (int i = tid; i < 16 * 32; i += 64) {
            const int t = i >> 5, m = i & 31;
            ws16[W3P_OFF + team * 512 + i] =
                (_Float16)((t < 10 && m < 25) ? W3[t * 25 + m] : 0.0f);
        }
        // wfr: [team][slot s][row r=out-channel (2)][k=t (16)]
        for (int i = tid; i < 5 * 2 * 16; i += 64) {
            const int s = i >> 5, r = (i >> 4) & 1, k = i & 15;
            ws16[WFR_OFF + team * 160 + i] =
                (_Float16)((k < 10) ? Wf[r * 100 + team * 50 + s * 10 + k] : 0.0f);
        }
        for (int i = tid; i < 32; i += 64) wsf[B2P_F + team * 32 + i] = (i < 25) ? B2[i] : 0.0f;
        for (int i = tid; i < 16; i += 64) wsf[B3P_F + team * 16 + i] = (i < 10) ? B3[i] : 0.0f;
    }
}

__device__ __forceinline__ f16x8 hfma8(f16x8 a, f16x8 b, f16x8 c) {
    return __builtin_elementwise_fma(a, b, c);
}
__device__ __forceinline__ f16x8 hrelu8(f16x8 a) {
    const f16x8 z = {0, 0, 0, 0, 0, 0, 0, 0};
    return __builtin_elementwise_max(a, z);
}
__device__ __forceinline__ f16x2 pkrtz(float a, float b) {
    return __builtin_bit_cast(f16x2, __builtin_amdgcn_cvt_pkrtz(a, b));
}

// 512 threads / 8 waves / 512 PERSISTENT blocks (2 per CU, all resident).
// Round-12 delta vs round 11 (36us match, unchanged by per-slot micro-opts):
// the ~36us behaved as a per-block fixed cost -- 2048 short-lived blocks each
// re-staged 61KB of LDS tables, barriered, ran ONE 128-sample tile, and died.
// Now each block stages once and grid-strides over 4 chunks: staging/dispatch
// cost /4, waves live 4x longer (steady-state latency hiding at 16 waves/CU).
// Slot pipeline, operand-swapped MFMAs, MFMA final layer: unchanged from r11.
__global__ __launch_bounds__(512)
__attribute__((amdgpu_waves_per_eu(4, 4)))
void match_predict(const float* __restrict__ feat, const _Float16* __restrict__ ws16,
                   const float* __restrict__ bf, float* __restrict__ out, int nB)
{
    __shared__ __align__(16) _Float16 sm16[L_END];
    __shared__ __align__(16) float    smf[96];

    const int tid = threadIdx.x;
    const int l  = tid & 63;
    const int c  = l & 15;          // sample column
    const int g  = l >> 4;          // k-chunk / row group
    const int wv = tid >> 6;

    // ---- stage tables: global ws -> LDS, ONCE per block ----
    for (int i = tid; i < 340 * 8; i += 512) {            // pre: 64 -> 72 stride
        const int r = i >> 3, ch = i & 7;
        *(f16x8*)(sm16 + L_PRE + r * 72 + ch * 8) =
            *(const f16x8*)(ws16 + PRE_OFF + r * 64 + ch * 8);
    }
    for (int i = tid; i < 16; i += 512)                   // w1g contiguous
        *(f16x8*)(sm16 + L_W1 + i * 8) = *(const f16x8*)(ws16 + W1G_OFF + i * 8);
    for (int i = tid; i < 64 * 8; i += 512) {             // w2: 64 -> 72 stride
        const int r = i >> 3, ch = i & 7;
        *(f16x8*)(sm16 + L_W2 + r * 72 + ch * 8) =
            *(const f16x8*)(ws16 + W2P_OFF + r * 64 + ch * 8);
    }
    for (int i = tid; i < 32 * 4; i += 512) {             // w3: 32 -> 40 stride
        const int r = i >> 2, ch = i & 3;
        *(f16x8*)(sm16 + L_W3 + r * 40 + ch * 8) =
            *(const f16x8*)(ws16 + W3P_OFF + r * 32 + ch * 8);
    }
    for (int i = tid; i < 40; i += 512) {                 // wfr: 32 -> 40 stride
        const int ts = i >> 2, ch = i & 3;
        *(f16x8*)(sm16 + L_WFR + ts * 40 + ch * 8) =
            *(const f16x8*)(ws16 + WFR_OFF + ts * 32 + ch * 8);
    }
    for (int i = tid; i < 24; i += 512)                   // 96 floats
        *(f32x4*)(smf + i * 4) = *(const f32x4*)((const float*)(ws16 + FOFF) + i * 4);
    __syncthreads();

    const int nchunks = (nB + 127) >> 7;

    for (int ck = blockIdx.x; ck < nchunks; ck += gridDim.x) {
        const int base = ck * 128 + wv * 16;
        if (base >= nB) continue;
        const int sample = base + c;
        const int sEff   = (sample < nB) ? sample : (nB - 1);

        const float4* f4 = reinterpret_cast<const float4*>(feat + (size_t)sEff * 12);
        const float4 v0 = f4[0], v1 = f4[1], v2 = f4[2];
        const float fr[12] = {v0.x, v0.y, v0.z, v0.w, v1.x, v1.y, v1.z, v1.w,
                              v2.x, v2.y, v2.z, v2.w};

        f32x4 aout = {0.f, 0.f, 0.f, 0.f};    // final-layer C, carried 10 slots

        // prime the pre-row pipeline with slot 0
        f16x8 pc0, pc1;
        {
            const int ci0 = (int)fr[2];
            const _Float16* p = sm16 + L_PRE + ci0 * 72;
            pc0 = *(const f16x8*)(p + g * 8);
            pc1 = *(const f16x8*)(p + 32 + g * 8);
        }

        #pragma unroll
        for (int team = 0; team < 2; ++team) {
            // ---- this team's fragments from LDS ----
            f16x8 w2A[2][2];                   // [mtile][kchunk]
            #pragma unroll
            for (int mt = 0; mt < 2; ++mt)
                #pragma unroll
                for (int kf = 0; kf < 2; ++kf)
                    w2A[mt][kf] = *(const f16x8*)(sm16 + L_W2
                                     + (team * 32 + mt * 16 + c) * 72 + kf * 32 + g * 8);
            const f16x4 w3A0 = *(const f16x4*)(sm16 + L_W3 + (team * 16 + c) * 40 + 4 * g);
            const f16x4 w3A1 = *(const f16x4*)(sm16 + L_W3 + (team * 16 + c) * 40 + 16 + 4 * g);
            const f16x8 w1gA = *(const f16x8*)(sm16 + L_W1 + team * 64 + g * 8);
            const f16x8 w1gB = *(const f16x8*)(sm16 + L_W1 + team * 64 + 32 + g * 8);
            f16x4 wfrA[5];
            #pragma unroll
            for (int s = 0; s < 5; ++s)        // 2 real rows; lanes c>=2 dup c&1
                wfrA[s] = *(const f16x4*)(sm16 + L_WFR + (team * 5 + s) * 40
                                          + (c & 1) * 16 + 4 * g);
            const f32x4 b2lo = *(const f32x4*)(smf + B2P_F + team * 32 + 4 * g);
            const f32x4 b2hi = *(const f32x4*)(smf + B2P_F + team * 32 + 16 + 4 * g);
            const f32x4 b3v  = *(const f32x4*)(smf + B3P_F + team * 16 + 4 * g);
            const _Float16 glh = (_Float16)fr[team];
            const f16x8 glv = {glh, glh, glh, glh, glh, glh, glh, glh};

            #pragma unroll
            for (int s5 = 0; s5 < 5; ++s5) {
                const int slot = team * 5 + s5;

                // issue next slot's pre-row reads before this slot's compute
                f16x8 pn0 = pc0, pn1 = pc1;
                if (slot < 9) {
                    const int cin = (int)fr[3 + slot];
                    const int tn = (slot + 1) / 5;          // literal after unroll
                    const _Float16* pn = sm16 + L_PRE + (tn * 170 + cin) * 72;
                    pn0 = *(const f16x8*)(pn + g * 8);
                    pn1 = *(const f16x8*)(pn + 32 + g * 8);
                }

                // h1^T B-frag (lane (c,g) = h1[sample c][k = chunk*32 + g*8 + i])
                const f16x8 h10 = hrelu8(hfma8(w1gA, glv, pc0));
                const f16x8 h11 = hrelu8(hfma8(w1gB, glv, pc1));

                // layer 2: h2^T[m][c] = W2 . h1^T, b2 as C-in
                f32x4 a0 = b2lo, a1 = b2hi;
                a0 = __builtin_amdgcn_mfma_f32_16x16x32_f16(w2A[0][0], h10, a0, 0, 0, 0);
                a0 = __builtin_amdgcn_mfma_f32_16x16x32_f16(w2A[0][1], h11, a0, 0, 0, 0);
                a1 = __builtin_amdgcn_mfma_f32_16x16x32_f16(w2A[1][0], h10, a1, 0, 0, 0);
                a1 = __builtin_amdgcn_mfma_f32_16x16x32_f16(w2A[1][1], h11, a1, 0, 0, 0);

                // relu + pack: lane (c,g) holds m=4g+q / 16+4g+q = K=16 B-frag
                const f16x2 p00 = pkrtz(fmaxf(a0[0], 0.f), fmaxf(a0[1], 0.f));
                const f16x2 p01 = pkrtz(fmaxf(a0[2], 0.f), fmaxf(a0[3], 0.f));
                const f16x2 p10 = pkrtz(fmaxf(a1[0], 0.f), fmaxf(a1[1], 0.f));
                const f16x2 p11 = pkrtz(fmaxf(a1[2], 0.f), fmaxf(a1[3], 0.f));
                const f16x4 b3t0 = {p00.x, p00.y, p01.x, p01.y};
                const f16x4 b3t1 = {p10.x, p10.y, p11.x, p11.y};

                // layer 3: h3^T[t][c] = W3 . h2^T, b3 as C-in
                f32x4 a3 = b3v;
                a3 = __builtin_amdgcn_mfma_f32_16x16x16f16(w3A0, b3t0, a3, 0, 0, 0);
                a3 = __builtin_amdgcn_mfma_f32_16x16x16f16(w3A1, b3t1, a3, 0, 0, 0);

                // final layer: B-frag = relu(h3) (k=4g+q=t), A = Wf rows,
                // C accumulates across slots.
                const f16x2 q0 = pkrtz(fmaxf(a3[0], 0.f), fmaxf(a3[1], 0.f));
                const f16x2 q1 = pkrtz(fmaxf(a3[2], 0.f), fmaxf(a3[3], 0.f));
                const f16x4 h3f = {q0.x, q0.y, q1.x, q1.y};
                aout = __builtin_amdgcn_mfma_f32_16x16x16f16(wfrA[s5], h3f, aout, 0, 0, 0);

                pc0 = pn0; pc1 = pn1;
            }
        }

        // aout: lane (c,g) holds C[row 4g+q][col c]; rows 0,1 = out0/out1.
        if (g == 0 && sample < nB) {
            reinterpret_cast<float2*>(out)[sample] =
                make_float2(aout[0] + bf[0], aout[1] + bf[1]);
        }
    }
}

extern "C" void kernel_launch(void* const* d_in, const int* in_sizes, int n_in,
                              void* d_out, int out_size, void* d_ws, size_t ws_size,
                              hipStream_t stream) {
    const float* feat = (const float*)d_in[0];
    const float* emb  = (const float*)d_in[1];
    const float* W1a  = (const float*)d_in[2];
    const float* b1a  = (const float*)d_in[3];
    const float* W2a  = (const float*)d_in[4];
    const float* b2a  = (const float*)d_in[5];
    const float* W3a  = (const float*)d_in[6];
    const float* b3a  = (const float*)d_in[7];
    const float* W1b  = (const float*)d_in[8];
    const float* b1b  = (const float*)d_in[9];
    const float* W2b  = (const float*)d_in[10];
    const float* b2b  = (const float*)d_in[11];
    const float* W3b  = (const float*)d_in[12];
    const float* b3b  = (const float*)d_in[13];
    const float* Wf   = (const float*)d_in[14];
    const float* bf   = (const float*)d_in[15];
    float* out = (float*)d_out;
    _Float16* ws16 = (_Float16*)d_ws;

    const int nB = in_sizes[0] / 12;

    precompute<<<dim3(171, 2), 64, 0, stream>>>(emb,
        W1a, b1a, W2a, b2a, W3a, b3a,
        W1b, b1b, W2b, b2b, W3b, b3b, Wf, ws16);

    const int nchunks = (nB + 127) / 128;
    const int blocks = (nchunks < 512) ? nchunks : 512;   // 2 per CU, persistent
    match_predict<<<blocks, 512, 0, stream>>>(feat, ws16, bf, out, nB);
}

// Round 13
// 35.470 us; speedup vs baseline: 6.6054x; 1.0227x over previous
//
#include <hip/hip_runtime.h>

typedef _Float16 f16x8 __attribute__((ext_vector_type(8)));
typedef _Float16 f16x4 __attribute__((ext_vector_type(4)));
typedef _Float16 f16x2 __attribute__((ext_vector_type(2)));
typedef float    f32x4 __attribute__((ext_vector_type(4)));

// ---- global ws layout (halfword units), produced by precompute ----
#define PRE_OFF   0
#define PRE_SZ    (2 * 170 * 64)
#define W1G_OFF   (PRE_OFF + PRE_SZ)          // 21760 (128 hw)
#define W2P_OFF   (W1G_OFF + 2 * 64)          // 21888 (4096 hw)
#define W3P_OFF   (W2P_OFF + 2 * 32 * 64)     // 25984 (1024 hw)
#define WFR_OFF   (W3P_OFF + 2 * 16 * 32)     // 27008 (320 hw)
#define H16_END   (WFR_OFF + 320)             // 27328
#define FOFF      H16_END
#define B2P_F     0
#define B3P_F     (B2P_F + 2 * 32)            // 64  (+32) -> 96 floats

// ---- LDS layout (halfword units; strides mult. of 8 hw for 16B alignment) ----
#define L_PRE   0
#define L_W1    24480
#define L_W2    (L_W1 + 128)                  // 24608
#define L_W3    (L_W2 + 64 * 72)              // 29216
#define L_WFR   (L_W3 + 32 * 40)              // 30496
#define L_END   (L_WFR + 10 * 40)             // 30896 hw = 61792 B

__global__ void precompute(const float* __restrict__ emb,
                           const float* __restrict__ W1a, const float* __restrict__ b1a,
                           const float* __restrict__ W2a, const float* __restrict__ b2a,
                           const float* __restrict__ W3a, const float* __restrict__ b3a,
                           const float* __restrict__ W1b, const float* __restrict__ b1b,
                           const float* __restrict__ W2b, const float* __restrict__ b2b,
                           const float* __restrict__ W3b, const float* __restrict__ b3b,
                           const float* __restrict__ Wf,
                           _Float16* __restrict__ ws16)
{
    const int team = blockIdx.y;
    const float* __restrict__ W1 = team ? W1b : W1a;
    const float* __restrict__ B1 = team ? b1b : b1a;
    const float* __restrict__ W2 = team ? W2b : W2a;
    const float* __restrict__ B2 = team ? b2b : b2a;
    const float* __restrict__ W3 = team ? W3b : W3a;
    const float* __restrict__ B3 = team ? b3b : b3a;
    float* __restrict__ wsf = (float*)(ws16 + FOFF);
    const int tid = threadIdx.x;

    if (blockIdx.x < 170) {
        const int cc = blockIdx.x;
        const int k = tid;
        float v = 0.0f;
        if (k < 50) {
            v = B1[k];
            for (int d = 0; d < 50; ++d)
                v = fmaf(W1[k * 51 + d], emb[cc * 50 + d], v);
        }
        ws16[PRE_OFF + team * 170 * 64 + cc * 64 + k] = (_Float16)v;
    } else {
        for (int i = tid; i < 64; i += 64)
            ws16[W1G_OFF + team * 64 + i] = (_Float16)((i < 50) ? W1[i * 51 + 50] : 0.0f);
        for (int i = tid; i < 32 * 64; i += 64) {
            const int m = i >> 6, k = i & 63;
            ws16[W2P_OFF + team * 2048 + i] =
                (_Float16)((m < 25 && k < 50) ? W2[m * 50 + k] : 0.0f);
        }
        for (int i = tid; i < 16 * 32; i += 64) {
            const int t = i >> 5, m = i & 31;
            ws16[W3P_OFF + team * 512 + i] =
                (_Float16)((t < 10 && m < 25) ? W3[t * 25 + m] : 0.0f);
        }
        for (int i = tid; i < 5 * 2 * 16; i += 64) {
            const int s = i >> 5, r = (i >> 4) & 1, k = i & 15;
            ws16[WFR_OFF + team * 160 + i] =
                (_Float16)((k < 10) ? Wf[r * 100 + team * 50 + s * 10 + k] : 0.0f);
        }
        for (int i = tid; i < 32; i += 64) wsf[B2P_F + team * 32 + i] = (i < 25) ? B2[i] : 0.0f;
        for (int i = tid; i < 16; i += 64) wsf[B3P_F + team * 16 + i] = (i < 10) ? B3[i] : 0.0f;
    }
}

__device__ __forceinline__ f16x8 hfma8(f16x8 a, f16x8 b, f16x8 c) {
    return __builtin_elementwise_fma(a, b, c);
}
__device__ __forceinline__ f16x8 hrelu8(f16x8 a) {
    const f16x8 z = {0, 0, 0, 0, 0, 0, 0, 0};
    return __builtin_elementwise_max(a, z);
}
__device__ __forceinline__ f16x2 pkrtz(float a, float b) {
    return __builtin_bit_cast(f16x2, __builtin_amdgcn_cvt_pkrtz(a, b));
}
__device__ __forceinline__ f16x8 splat8(_Float16 h) {
    return (f16x8){h, h, h, h, h, h, h, h};
}

// 512 threads / 8 waves / 512 persistent blocks. Round-13 delta vs round 12
// (33us match; LDS pipe ~16.5us busy, half of it chunk-invariant fragment
// re-loads; both pipes <25% busy from serial chains): each wave now runs TWO
// independent 16-sample sets per chunk. The per-team fragment loads feed both
// sets (DS/sample -35%), and the two slot chains give 2x ILP against the
// MFMA/LDS latency bubbles. Champion indices packed 2/int, glicko as f16x2,
// wfr load moved into the slot body to stay under the 128-VGPR / 16-waves-CU
// occupancy point.
__global__ __launch_bounds__(512)
__attribute__((amdgpu_waves_per_eu(4, 4)))
void match_predict(const float* __restrict__ feat, const _Float16* __restrict__ ws16,
                   const float* __restrict__ bf, float* __restrict__ out, int nB)
{
    __shared__ __align__(16) _Float16 sm16[L_END];
    __shared__ __align__(16) float    smf[96];

    const int tid = threadIdx.x;
    const int l  = tid & 63;
    const int c  = l & 15;          // sample column
    const int g  = l >> 4;          // k-chunk / row group
    const int wv = tid >> 6;

    // ---- stage tables: global ws -> LDS, once per block ----
    for (int i = tid; i < 340 * 8; i += 512) {
        const int r = i >> 3, ch = i & 7;
        *(f16x8*)(sm16 + L_PRE + r * 72 + ch * 8) =
            *(const f16x8*)(ws16 + PRE_OFF + r * 64 + ch * 8);
    }
    for (int i = tid; i < 16; i += 512)
        *(f16x8*)(sm16 + L_W1 + i * 8) = *(const f16x8*)(ws16 + W1G_OFF + i * 8);
    for (int i = tid; i < 64 * 8; i += 512) {
        const int r = i >> 3, ch = i & 7;
        *(f16x8*)(sm16 + L_W2 + r * 72 + ch * 8) =
            *(const f16x8*)(ws16 + W2P_OFF + r * 64 + ch * 8);
    }
    for (int i = tid; i < 32 * 4; i += 512) {
        const int r = i >> 2, ch = i & 3;
        *(f16x8*)(sm16 + L_W3 + r * 40 + ch * 8) =
            *(const f16x8*)(ws16 + W3P_OFF + r * 32 + ch * 8);
    }
    for (int i = tid; i < 40; i += 512) {
        const int ts = i >> 2, ch = i & 3;
        *(f16x8*)(sm16 + L_WFR + ts * 40 + ch * 8) =
            *(const f16x8*)(ws16 + WFR_OFF + ts * 32 + ch * 8);
    }
    for (int i = tid; i < 24; i += 512)
        *(f32x4*)(smf + i * 4) = *(const f32x4*)((const float*)(ws16 + FOFF) + i * 4);
    __syncthreads();

    const float bf0 = bf[0], bf1 = bf[1];
    const int nchunks = (nB + 255) >> 8;    // 256 samples per block-chunk

    for (int ck = blockIdx.x; ck < nchunks; ck += gridDim.x) {
        const int base = ck * 256 + wv * 32;
        if (base >= nB) continue;
        const int sA = base + c;
        const int sB = base + 16 + c;
        const int sAe = (sA < nB) ? sA : (nB - 1);
        const int sBe = (sB < nB) ? sB : (nB - 1);

        // features: glicko packed f16x2, champion indices packed 2-per-int
        const float4* fA4 = reinterpret_cast<const float4*>(feat + (size_t)sAe * 12);
        const float4* fB4 = reinterpret_cast<const float4*>(feat + (size_t)sBe * 12);
        const float4 A0 = fA4[0], A1 = fA4[1], A2 = fA4[2];
        const float4 B0 = fB4[0], B1v = fB4[1], B2v = fB4[2];
        const f16x2 glA = {(_Float16)A0.x, (_Float16)A0.y};
        const f16x2 glB = {(_Float16)B0.x, (_Float16)B0.y};
        unsigned ciA[5], ciB[5];
        ciA[0] = (unsigned)A0.z  | ((unsigned)A0.w  << 16);
        ciA[1] = (unsigned)A1.x  | ((unsigned)A1.y  << 16);
        ciA[2] = (unsigned)A1.z  | ((unsigned)A1.w  << 16);
        ciA[3] = (unsigned)A2.x  | ((unsigned)A2.y  << 16);
        ciA[4] = (unsigned)A2.z  | ((unsigned)A2.w  << 16);
        ciB[0] = (unsigned)B0.z  | ((unsigned)B0.w  << 16);
        ciB[1] = (unsigned)B1v.x | ((unsigned)B1v.y << 16);
        ciB[2] = (unsigned)B1v.z | ((unsigned)B1v.w << 16);
        ciB[3] = (unsigned)B2v.x | ((unsigned)B2v.y << 16);
        ciB[4] = (unsigned)B2v.z | ((unsigned)B2v.w << 16);

        f32x4 aoutA = {0.f, 0.f, 0.f, 0.f};
        f32x4 aoutB = {0.f, 0.f, 0.f, 0.f};

        // prime pre-row pipelines (team 0, slot 0)
        f16x8 pcA0, pcA1, pcB0, pcB1;
        {
            const _Float16* pA = sm16 + L_PRE + (ciA[0] & 0xFFFF) * 72;
            const _Float16* pB = sm16 + L_PRE + (ciB[0] & 0xFFFF) * 72;
            pcA0 = *(const f16x8*)(pA + g * 8);
            pcA1 = *(const f16x8*)(pA + 32 + g * 8);
            pcB0 = *(const f16x8*)(pB + g * 8);
            pcB1 = *(const f16x8*)(pB + 32 + g * 8);
        }

        #pragma unroll
        for (int team = 0; team < 2; ++team) {
            // ---- team fragments (shared by both sample sets) ----
            f16x8 w2A[2][2];
            #pragma unroll
            for (int mt = 0; mt < 2; ++mt)
                #pragma unroll
                for (int kf = 0; kf < 2; ++kf)
                    w2A[mt][kf] = *(const f16x8*)(sm16 + L_W2
                                     + (team * 32 + mt * 16 + c) * 72 + kf * 32 + g * 8);
            const f16x4 w3A0 = *(const f16x4*)(sm16 + L_W3 + (team * 16 + c) * 40 + 4 * g);
            const f16x4 w3A1 = *(const f16x4*)(sm16 + L_W3 + (team * 16 + c) * 40 + 16 + 4 * g);
            const f16x8 w1gA = *(const f16x8*)(sm16 + L_W1 + team * 64 + g * 8);
            const f16x8 w1gB = *(const f16x8*)(sm16 + L_W1 + team * 64 + 32 + g * 8);
            const f32x4 b2lo = *(const f32x4*)(smf + B2P_F + team * 32 + 4 * g);
            const f32x4 b2hi = *(const f32x4*)(smf + B2P_F + team * 32 + 16 + 4 * g);
            const f32x4 b3v  = *(const f32x4*)(smf + B3P_F + team * 16 + 4 * g);
            const f16x8 glvA = splat8(team ? glA.y : glA.x);
            const f16x8 glvB = splat8(team ? glB.y : glB.x);

            #pragma unroll
            for (int s5 = 0; s5 < 5; ++s5) {
                const int slot = team * 5 + s5;

                // prefetch next slot's pre-rows for both sets
                f16x8 pnA0 = pcA0, pnA1 = pcA1, pnB0 = pcB0, pnB1 = pcB1;
                if (slot < 9) {
                    const int j = slot + 1;
                    const int tn = j / 5;                 // literal after unroll
                    const int cA2 = (ciA[j >> 1] >> ((j & 1) * 16)) & 0xFFFF;
                    const int cB2 = (ciB[j >> 1] >> ((j & 1) * 16)) & 0xFFFF;
                    const _Float16* pA = sm16 + L_PRE + (tn * 170 + cA2) * 72;
                    const _Float16* pB = sm16 + L_PRE + (tn * 170 + cB2) * 72;
                    pnA0 = *(const f16x8*)(pA + g * 8);
                    pnA1 = *(const f16x8*)(pA + 32 + g * 8);
                    pnB0 = *(const f16x8*)(pB + g * 8);
                    pnB1 = *(const f16x8*)(pB + 32 + g * 8);
                }

                // per-slot Wf A-frag (shared by both sets)
                const f16x4 wfr = *(const f16x4*)(sm16 + L_WFR + (team * 5 + s5) * 40
                                                  + (c & 1) * 16 + 4 * g);

                // ---- set A ----
                {
                    const f16x8 h10 = hrelu8(hfma8(w1gA, glvA, pcA0));
                    const f16x8 h11 = hrelu8(hfma8(w1gB, glvA, pcA1));
                    f32x4 a0 = b2lo, a1 = b2hi;
                    a0 = __builtin_amdgcn_mfma_f32_16x16x32_f16(w2A[0][0], h10, a0, 0, 0, 0);
                    a0 = __builtin_amdgcn_mfma_f32_16x16x32_f16(w2A[0][1], h11, a0, 0, 0, 0);
                    a1 = __builtin_amdgcn_mfma_f32_16x16x32_f16(w2A[1][0], h10, a1, 0, 0, 0);
                    a1 = __builtin_amdgcn_mfma_f32_16x16x32_f16(w2A[1][1], h11, a1, 0, 0, 0);
                    const f16x2 p00 = pkrtz(fmaxf(a0[0], 0.f), fmaxf(a0[1], 0.f));
                    const f16x2 p01 = pkrtz(fmaxf(a0[2], 0.f), fmaxf(a0[3], 0.f));
                    const f16x2 p10 = pkrtz(fmaxf(a1[0], 0.f), fmaxf(a1[1], 0.f));
                    const f16x2 p11 = pkrtz(fmaxf(a1[2], 0.f), fmaxf(a1[3], 0.f));
                    const f16x4 b3t0 = {p00.x, p00.y, p01.x, p01.y};
                    const f16x4 b3t1 = {p10.x, p10.y, p11.x, p11.y};
                    f32x4 a3 = b3v;
                    a3 = __builtin_amdgcn_mfma_f32_16x16x16f16(w3A0, b3t0, a3, 0, 0, 0);
                    a3 = __builtin_amdgcn_mfma_f32_16x16x16f16(w3A1, b3t1, a3, 0, 0, 0);
                    const f16x2 q0 = pkrtz(fmaxf(a3[0], 0.f), fmaxf(a3[1], 0.f));
                    const f16x2 q1 = pkrtz(fmaxf(a3[2], 0.f), fmaxf(a3[3], 0.f));
                    const f16x4 h3f = {q0.x, q0.y, q1.x, q1.y};
                    aoutA = __builtin_amdgcn_mfma_f32_16x16x16f16(wfr, h3f, aoutA, 0, 0, 0);
                }
                // ---- set B ----
                {
                    const f16x8 h10 = hrelu8(hfma8(w1gA, glvB, pcB0));
                    const f16x8 h11 = hrelu8(hfma8(w1gB, glvB, pcB1));
                    f32x4 a0 = b2lo, a1 = b2hi;
                    a0 = __builtin_amdgcn_mfma_f32_16x16x32_f16(w2A[0][0], h10, a0, 0, 0, 0);
                    a0 = __builtin_amdgcn_mfma_f32_16x16x32_f16(w2A[0][1], h11, a0, 0, 0, 0);
                    a1 = __builtin_amdgcn_mfma_f32_16x16x32_f16(w2A[1][0], h10, a1, 0, 0, 0);
                    a1 = __builtin_amdgcn_mfma_f32_16x16x32_f16(w2A[1][1], h11, a1, 0, 0, 0);
                    const f16x2 p00 = pkrtz(fmaxf(a0[0], 0.f), fmaxf(a0[1], 0.f));
                    const f16x2 p01 = pkrtz(fmaxf(a0[2], 0.f), fmaxf(a0[3], 0.f));
                    const f16x2 p10 = pkrtz(fmaxf(a1[0], 0.f), fmaxf(a1[1], 0.f));
                    const f16x2 p11 = pkrtz(fmaxf(a1[2], 0.f), fmaxf(a1[3], 0.f));
                    const f16x4 b3t0 = {p00.x, p00.y, p01.x, p01.y};
                    const f16x4 b3t1 = {p10.x, p10.y, p11.x, p11.y};
                    f32x4 a3 = b3v;
                    a3 = __builtin_amdgcn_mfma_f32_16x16x16f16(w3A0, b3t0, a3, 0, 0, 0);
                    a3 = __builtin_amdgcn_mfma_f32_16x16x16f16(w3A1, b3t1, a3, 0, 0, 0);
                    const f16x2 q0 = pkrtz(fmaxf(a3[0], 0.f), fmaxf(a3[1], 0.f));
                    const f16x2 q1 = pkrtz(fmaxf(a3[2], 0.f), fmaxf(a3[3], 0.f));
                    const f16x4 h3f = {q0.x, q0.y, q1.x, q1.y};
                    aoutB = __builtin_amdgcn_mfma_f32_16x16x16f16(wfr, h3f, aoutB, 0, 0, 0);
                }

                pcA0 = pnA0; pcA1 = pnA1; pcB0 = pnB0; pcB1 = pnB1;
            }
        }

        if (g == 0) {
            if (sA < nB)
                reinterpret_cast<float2*>(out)[sA] =
                    make_float2(aoutA[0] + bf0, aoutA[1] + bf1);
            if (sB < nB)
                reinterpret_cast<float2*>(out)[sB] =
                    make_float2(aoutB[0] + bf0, aoutB[1] + bf1);
        }
    }
}

extern "C" void kernel_launch(void* const* d_in, const int* in_sizes, int n_in,
                              void* d_out, int out_size, void* d_ws, size_t ws_size,
                              hipStream_t stream) {
    const float* feat = (const float*)d_in[0];
    const float* emb  = (const float*)d_in[1];
    const float* W1a  = (const float*)d_in[2];
    const float* b1a  = (const float*)d_in[3];
    const float* W2a  = (const float*)d_in[4];
    const float* b2a  = (const float*)d_in[5];
    const float* W3a  = (const float*)d_in[6];
    const float* b3a  = (const float*)d_in[7];
    const float* W1b  = (const float*)d_in[8];
    const float* b1b  = (const float*)d_in[9];
    const float* W2b  = (const float*)d_in[10];
    const float* b2b  = (const float*)d_in[11];
    const float* W3b  = (const float*)d_in[12];
    const float* b3b  = (const float*)d_in[13];
    const float* Wf   = (const float*)d_in[14];
    const float* bf   = (const float*)d_in[15];
    float* out = (float*)d_out;
    _Float16* ws16 = (_Float16*)d_ws;

    const int nB = in_sizes[0] / 12;

    precompute<<<dim3(171, 2), 64, 0, stream>>>(emb,
        W1a, b1a, W2a, b2a, W3a, b3a,
        W1b, b1b, W2b, b2b, W3b, b3b, Wf, ws16);

    const int nchunks = (nB + 255) / 256;
    const int blocks = (nchunks < 512) ? nchunks : 512;   // persistent, 2 per CU
    match_predict<<<blocks, 512, 0, stream>>>(feat, ws16, bf, out, nB);
}